// Round 1
// baseline (1652.080 us; speedup 1.0000x reference)
//
#include <hip/hip_runtime.h>
#include <hip/hip_bf16.h>
#include <math.h>

#define N_NODES 32768
#define E_EDGES 262144
#define F_INF   74
#define D0      128
#define D1      256
#define BN_EPS  1e-5f

__device__ __forceinline__ float gelu_exact(float x) {
    return 0.5f * x * (1.0f + erff(x * 0.70710678118654752440f));
}

// ---------- small prep kernels ----------

__global__ void k_transpose_winit(const float* __restrict__ W, float* __restrict__ WT) {
    int idx = blockIdx.x * 256 + threadIdx.x;
    if (idx < F_INF * D0) {
        int f = idx / D0, c = idx % D0;
        WT[f * D0 + c] = W[c * F_INF + f];
    }
}

__global__ void k_transpose_rw(const float* __restrict__ W, float* __restrict__ WT) {
    int idx = blockIdx.x * 256 + threadIdx.x;  // D0*D1 = 32768 threads
    int k = idx / D1, c = idx % D1;
    WT[k * D1 + c] = W[c * D0 + k];
}

__global__ void k_degrees(const int* __restrict__ src, const int* __restrict__ dst,
                          int* __restrict__ deg) {
    int e = blockIdx.x * 256 + threadIdx.x;
    if (e < E_EDGES) {
        atomicAdd(&deg[src[e]], 1);
        atomicAdd(&deg[N_NODES + dst[e]], 1);
    }
}

__global__ void k_rsq(const int* __restrict__ deg, float* __restrict__ rsq_out,
                      float* __restrict__ rsq_in) {
    int i = blockIdx.x * 256 + threadIdx.x;
    if (i < N_NODES) {
        int d_o = deg[i];           if (d_o < 1) d_o = 1;
        int d_i = deg[N_NODES + i]; if (d_i < 1) d_i = 1;
        rsq_out[i] = 1.0f / sqrtf((float)d_o);
        rsq_in[i]  = 1.0f / sqrtf((float)d_i);
    }
}

// ---------- init GEMM: h0 = node_feats @ W_init^T  [N,74]x[74,128] ----------

__global__ __launch_bounds__(256) void k_init_gemm(
    const float* __restrict__ nf, const float* __restrict__ WT,
    float* __restrict__ h0) {
    __shared__ float sNF[64 * 76];
    int nb = blockIdx.x * 64;
    int tid = threadIdx.x;
    for (int idx = tid; idx < 64 * F_INF; idx += 256) {
        int row = idx / F_INF, f = idx % F_INF;
        sNF[row * 76 + f] = nf[(size_t)nb * F_INF + idx];  // contiguous global read
    }
    __syncthreads();
    int tc = tid & 31;   // cols tc*4 .. +3 (of 128)
    int tn = tid >> 5;   // 0..7 -> nodes tn*8 .. +7
    int c0 = tc * 4;
    float acc[8][4];
    #pragma unroll
    for (int i = 0; i < 8; i++)
        #pragma unroll
        for (int j = 0; j < 4; j++) acc[i][j] = 0.f;
    for (int k = 0; k < F_INF; k++) {
        float4 w = *reinterpret_cast<const float4*>(&WT[k * D0 + c0]);
        #pragma unroll
        for (int i = 0; i < 8; i++) {
            float a = sNF[(tn * 8 + i) * 76 + k];
            acc[i][0] += a * w.x; acc[i][1] += a * w.y;
            acc[i][2] += a * w.z; acc[i][3] += a * w.w;
        }
    }
    #pragma unroll
    for (int i = 0; i < 8; i++) {
        float4 o = make_float4(acc[i][0], acc[i][1], acc[i][2], acc[i][3]);
        *reinterpret_cast<float4*>(&h0[(size_t)(nb + tn * 8 + i) * D0 + c0]) = o;
    }
}

// ---------- edge scatter: agg[dst] += x[src] * rsq_out[src] ----------

template<int DIM>
__global__ __launch_bounds__(256) void k_scatter(
    const float* __restrict__ x, const float* __restrict__ rsq_out,
    const int* __restrict__ src, const int* __restrict__ dst,
    float* __restrict__ agg) {
    const int PF = DIM / 4;
    long long idx = (long long)blockIdx.x * 256 + threadIdx.x;
    int e = (int)(idx / PF);
    int f = (int)(idx % PF) * 4;
    if (e < E_EDGES) {
        int s = src[e], d = dst[e];
        float sc = rsq_out[s];
        float4 v = *reinterpret_cast<const float4*>(&x[(size_t)s * DIM + f]);
        atomicAdd(&agg[(size_t)d * DIM + f + 0], v.x * sc);
        atomicAdd(&agg[(size_t)d * DIM + f + 1], v.y * sc);
        atomicAdd(&agg[(size_t)d * DIM + f + 2], v.z * sc);
        atomicAdd(&agg[(size_t)d * DIM + f + 3], v.w * sc);
    }
}

// ---------- layer1: t1 = gelu((agg1*rsq_in) @ w1 + b1) + h0 @ rwT + rb ----------

__global__ __launch_bounds__(256) void k_layer1_gemm(
    const float* __restrict__ agg, const float* __restrict__ h0,
    const float* __restrict__ rsq_in,
    const float* __restrict__ w1,   // [128][256] k-major
    const float* __restrict__ rwT,  // [128][256] k-major
    const float* __restrict__ b1, const float* __restrict__ rb,
    float* __restrict__ t1) {
    __shared__ float sA[64 * 132];
    __shared__ float sH[64 * 132];
    int nb = blockIdx.x * 64;
    int cb = blockIdx.y * 64;
    int tid = threadIdx.x;
    #pragma unroll
    for (int j = 0; j < 8; j++) {
        int idx = tid + j * 256;
        int row = idx >> 5;
        int k4 = (idx & 31) * 4;
        float sc = rsq_in[nb + row];
        float4 a = *reinterpret_cast<const float4*>(&agg[(size_t)(nb + row) * D0 + k4]);
        float4 h = *reinterpret_cast<const float4*>(&h0[(size_t)(nb + row) * D0 + k4]);
        *reinterpret_cast<float4*>(&sA[row * 132 + k4]) =
            make_float4(a.x * sc, a.y * sc, a.z * sc, a.w * sc);
        *reinterpret_cast<float4*>(&sH[row * 132 + k4]) = h;
    }
    __syncthreads();
    int tc = tid & 15, tn = tid >> 4;
    int c0 = cb + tc * 4;
    int r0 = tn * 4;
    float accG[4][4] = {{0.f}}, accR[4][4] = {{0.f}};
    for (int k = 0; k < D0; k++) {
        float4 w  = *reinterpret_cast<const float4*>(&w1[k * D1 + c0]);
        float4 rw = *reinterpret_cast<const float4*>(&rwT[k * D1 + c0]);
        #pragma unroll
        for (int i = 0; i < 4; i++) {
            float a = sA[(r0 + i) * 132 + k];
            float h = sH[(r0 + i) * 132 + k];
            accG[i][0] += a * w.x;  accG[i][1] += a * w.y;
            accG[i][2] += a * w.z;  accG[i][3] += a * w.w;
            accR[i][0] += h * rw.x; accR[i][1] += h * rw.y;
            accR[i][2] += h * rw.z; accR[i][3] += h * rw.w;
        }
    }
    float4 bb  = *reinterpret_cast<const float4*>(&b1[c0]);
    float4 rbb = *reinterpret_cast<const float4*>(&rb[c0]);
    #pragma unroll
    for (int i = 0; i < 4; i++) {
        float4 o;
        o.x = gelu_exact(accG[i][0] + bb.x) + accR[i][0] + rbb.x;
        o.y = gelu_exact(accG[i][1] + bb.y) + accR[i][1] + rbb.y;
        o.z = gelu_exact(accG[i][2] + bb.z) + accR[i][2] + rbb.z;
        o.w = gelu_exact(accG[i][3] + bb.w) + accR[i][3] + rbb.w;
        *reinterpret_cast<float4*>(&t1[(size_t)(nb + r0 + i) * D1 + c0]) = o;
    }
}

// ---------- layer2: t2 = gelu((agg2*rsq_in) @ w2 + b2) + h1 ----------

__global__ __launch_bounds__(256) void k_layer2_gemm(
    const float* __restrict__ agg, const float* __restrict__ rsq_in,
    const float* __restrict__ w2,  // [256][256] k-major
    const float* __restrict__ b2,
    const float* __restrict__ h1, float* __restrict__ t2) {
    __shared__ float sA[64 * 260];
    int nb = blockIdx.x * 64, cb = blockIdx.y * 64, tid = threadIdx.x;
    #pragma unroll
    for (int j = 0; j < 16; j++) {
        int idx = tid + j * 256;
        int row = idx >> 6;
        int k4 = (idx & 63) * 4;
        float sc = rsq_in[nb + row];
        float4 a = *reinterpret_cast<const float4*>(&agg[(size_t)(nb + row) * D1 + k4]);
        *reinterpret_cast<float4*>(&sA[row * 260 + k4]) =
            make_float4(a.x * sc, a.y * sc, a.z * sc, a.w * sc);
    }
    __syncthreads();
    int tc = tid & 15, tn = tid >> 4;
    int c0 = cb + tc * 4, r0 = tn * 4;
    float acc[4][4] = {{0.f}};
    for (int k = 0; k < D1; k++) {
        float4 w = *reinterpret_cast<const float4*>(&w2[k * D1 + c0]);
        #pragma unroll
        for (int i = 0; i < 4; i++) {
            float a = sA[(r0 + i) * 260 + k];
            acc[i][0] += a * w.x; acc[i][1] += a * w.y;
            acc[i][2] += a * w.z; acc[i][3] += a * w.w;
        }
    }
    float4 bb = *reinterpret_cast<const float4*>(&b2[c0]);
    #pragma unroll
    for (int i = 0; i < 4; i++) {
        float4 hv = *reinterpret_cast<const float4*>(&h1[(size_t)(nb + r0 + i) * D1 + c0]);
        float4 o;
        o.x = gelu_exact(acc[i][0] + bb.x) + hv.x;
        o.y = gelu_exact(acc[i][1] + bb.y) + hv.y;
        o.z = gelu_exact(acc[i][2] + bb.z) + hv.z;
        o.w = gelu_exact(acc[i][3] + bb.w) + hv.w;
        *reinterpret_cast<float4*>(&t2[(size_t)(nb + r0 + i) * D1 + c0]) = o;
    }
}

// ---------- BatchNorm ----------

__global__ __launch_bounds__(256) void k_bn_stats(const float* __restrict__ x,
                                                  float* __restrict__ sums) {
    int col = threadIdx.x;        // 256 channels
    int base = blockIdx.x * 128;  // 128 nodes per block
    float s = 0.f, q = 0.f;
    for (int i = 0; i < 128; i++) {
        float v = x[(size_t)(base + i) * D1 + col];
        s += v; q += v * v;
    }
    atomicAdd(&sums[col], s);
    atomicAdd(&sums[D1 + col], q);
}

__global__ __launch_bounds__(256) void k_bn_apply(
    const float* __restrict__ x, const float* __restrict__ sums,
    const float* __restrict__ g, const float* __restrict__ b,
    float* __restrict__ y) {
    int idx = blockIdx.x * 256 + threadIdx.x;   // over N*D1/4 float4s
    int c4 = (idx & 63) * 4;
    float4 v  = *reinterpret_cast<const float4*>(&x[(size_t)idx * 4]);
    float4 sv = *reinterpret_cast<const float4*>(&sums[c4]);
    float4 qv = *reinterpret_cast<const float4*>(&sums[D1 + c4]);
    float4 gv = *reinterpret_cast<const float4*>(&g[c4]);
    float4 bv = *reinterpret_cast<const float4*>(&b[c4]);
    const float invN = 1.0f / (float)N_NODES;
    float4 o;
    {
        float m = sv.x * invN; float var = qv.x * invN - m * m;
        o.x = (v.x - m) * (1.0f / sqrtf(var + BN_EPS)) * gv.x + bv.x;
    }
    {
        float m = sv.y * invN; float var = qv.y * invN - m * m;
        o.y = (v.y - m) * (1.0f / sqrtf(var + BN_EPS)) * gv.y + bv.y;
    }
    {
        float m = sv.z * invN; float var = qv.z * invN - m * m;
        o.z = (v.z - m) * (1.0f / sqrtf(var + BN_EPS)) * gv.z + bv.z;
    }
    {
        float m = sv.w * invN; float var = qv.w * invN - m * m;
        o.w = (v.w - m) * (1.0f / sqrtf(var + BN_EPS)) * gv.w + bv.w;
    }
    *reinterpret_cast<float4*>(&y[(size_t)idx * 4]) = o;
}

// ---------- launch ----------

extern "C" void kernel_launch(void* const* d_in, const int* in_sizes, int n_in,
                              void* d_out, int out_size, void* d_ws, size_t ws_size,
                              hipStream_t stream) {
    const float* node_feats = (const float*)d_in[0];
    const float* W_init     = (const float*)d_in[1];
    const float* gcn_w1     = (const float*)d_in[2];
    const float* gcn_b1     = (const float*)d_in[3];
    const float* res_w1     = (const float*)d_in[4];
    const float* res_b1     = (const float*)d_in[5];
    const float* bn_g1      = (const float*)d_in[6];
    const float* bn_b1      = (const float*)d_in[7];
    const float* gcn_w2     = (const float*)d_in[8];
    const float* gcn_b2     = (const float*)d_in[9];
    const float* bn_g2      = (const float*)d_in[10];
    const float* bn_b2      = (const float*)d_in[11];
    const int*   edge_src   = (const int*)d_in[12];
    const int*   edge_dst   = (const int*)d_in[13];
    float* out = (float*)d_out;

    float* ws = (float*)d_ws;
    float* h0   = ws;                            // N*128
    float* agg1 = ws + (size_t)N_NODES * 128;    // N*128
    float* t1   = ws + (size_t)N_NODES * 256;    // N*256  (reused as agg2)
    float* h1   = ws + (size_t)N_NODES * 512;    // N*256
    float* t2   = ws;                            // reuse [0, N*256)
    float* agg2 = t1;
    float* rsq_out = ws + (size_t)N_NODES * 768;
    float* rsq_in  = rsq_out + N_NODES;
    int*   degi    = (int*)(rsq_in + N_NODES);   // 2N ints
    float* stats1  = (float*)(degi + 2 * N_NODES);  // 512 floats (sum, sumsq)
    float* stats2  = stats1 + 512;                  // 512 floats
    float* WT      = stats2 + 512;                  // 74*128
    float* rwT     = WT + F_INF * D0;               // 128*256

    hipMemsetAsync(degi, 0, 2 * N_NODES * sizeof(int), stream);
    hipMemsetAsync(stats1, 0, 1024 * sizeof(float), stream);
    hipMemsetAsync(agg1, 0, (size_t)N_NODES * 128 * sizeof(float), stream);

    k_degrees<<<(E_EDGES + 255) / 256, 256, 0, stream>>>(edge_src, edge_dst, degi);
    k_rsq<<<(N_NODES + 255) / 256, 256, 0, stream>>>(degi, rsq_out, rsq_in);
    k_transpose_winit<<<(F_INF * D0 + 255) / 256, 256, 0, stream>>>(W_init, WT);
    k_transpose_rw<<<(D0 * D1) / 256, 256, 0, stream>>>(res_w1, rwT);

    k_init_gemm<<<N_NODES / 64, 256, 0, stream>>>(node_feats, WT, h0);

    k_scatter<128><<<(E_EDGES * 32) / 256, 256, 0, stream>>>(h0, rsq_out, edge_src, edge_dst, agg1);

    k_layer1_gemm<<<dim3(N_NODES / 64, 4), 256, 0, stream>>>(
        agg1, h0, rsq_in, gcn_w1, rwT, gcn_b1, res_b1, t1);

    k_bn_stats<<<N_NODES / 128, 256, 0, stream>>>(t1, stats1);
    k_bn_apply<<<(N_NODES * 64) / 256, 256, 0, stream>>>(t1, stats1, bn_g1, bn_b1, h1);

    hipMemsetAsync(agg2, 0, (size_t)N_NODES * 256 * sizeof(float), stream);
    k_scatter<256><<<(E_EDGES * 64) / 256, 256, 0, stream>>>(h1, rsq_out, edge_src, edge_dst, agg2);

    k_layer2_gemm<<<dim3(N_NODES / 64, 4), 256, 0, stream>>>(
        agg2, rsq_in, gcn_w2, gcn_b2, h1, t2);

    k_bn_stats<<<N_NODES / 128, 256, 0, stream>>>(t2, stats2);
    k_bn_apply<<<(N_NODES * 64) / 256, 256, 0, stream>>>(t2, stats2, bn_g2, bn_b2, out);
}

// Round 2
// 422.931 us; speedup vs baseline: 3.9063x; 3.9063x over previous
//
#include <hip/hip_runtime.h>
#include <hip/hip_bf16.h>
#include <math.h>

#define N_NODES 32768
#define E_EDGES 262144
#define F_INF   74
#define D0      128
#define D1      256
#define BN_EPS  1e-5f

__device__ __forceinline__ float gelu_exact(float x) {
    return 0.5f * x * (1.0f + erff(x * 0.70710678118654752440f));
}

// ---------- small prep kernels ----------

__global__ void k_transpose_winit(const float* __restrict__ W, float* __restrict__ WT) {
    int idx = blockIdx.x * 256 + threadIdx.x;
    if (idx < F_INF * D0) {
        int f = idx / D0, c = idx % D0;
        WT[f * D0 + c] = W[c * F_INF + f];
    }
}

__global__ void k_transpose_rw(const float* __restrict__ W, float* __restrict__ WT) {
    int idx = blockIdx.x * 256 + threadIdx.x;  // D0*D1 = 32768 threads
    int k = idx / D1, c = idx % D1;
    WT[k * D1 + c] = W[c * D0 + k];
}

__global__ void k_degrees(const int* __restrict__ src, const int* __restrict__ dst,
                          int* __restrict__ deg) {
    int e = blockIdx.x * 256 + threadIdx.x;
    if (e < E_EDGES) {
        atomicAdd(&deg[src[e]], 1);
        atomicAdd(&deg[N_NODES + dst[e]], 1);
    }
}

__global__ void k_rsq(const int* __restrict__ deg, float* __restrict__ rsq_out,
                      float* __restrict__ rsq_in) {
    int i = blockIdx.x * 256 + threadIdx.x;
    if (i < N_NODES) {
        int d_o = deg[i];           if (d_o < 1) d_o = 1;
        int d_i = deg[N_NODES + i]; if (d_i < 1) d_i = 1;
        rsq_out[i] = 1.0f / sqrtf((float)d_o);
        rsq_in[i]  = 1.0f / sqrtf((float)d_i);
    }
}

// ---------- CSR build: exclusive scan of in-degrees ----------

__global__ __launch_bounds__(1024) void k_scan(const int* __restrict__ deg_in,
                                               int* __restrict__ row_off) {
    __shared__ int part[1024];
    int t = threadIdx.x;
    int base = t * 32;
    int loc[32];
    int s = 0;
    #pragma unroll
    for (int i = 0; i < 32; i++) { loc[i] = s; s += deg_in[base + i]; }
    part[t] = s;
    __syncthreads();
    for (int off = 1; off < 1024; off <<= 1) {
        int v = 0;
        if (t >= off) v = part[t - off];
        __syncthreads();
        if (t >= off) part[t] += v;
        __syncthreads();
    }
    int pre = (t == 0) ? 0 : part[t - 1];
    #pragma unroll
    for (int i = 0; i < 32; i++) row_off[base + i] = pre + loc[i];
    if (t == 1023) row_off[N_NODES] = part[1023];
}

__global__ void k_fill(const int* __restrict__ src, const int* __restrict__ dst,
                       const int* __restrict__ row_off, int* __restrict__ cursor,
                       int* __restrict__ csr_src) {
    int e = blockIdx.x * 256 + threadIdx.x;
    if (e < E_EDGES) {
        int d = dst[e];
        int slot = atomicAdd(&cursor[d], 1);
        csr_src[row_off[d] + slot] = src[e];
    }
}

// ---------- init GEMM: h0 = node_feats @ W_init^T  [N,74]x[74,128] ----------

__global__ __launch_bounds__(256) void k_init_gemm(
    const float* __restrict__ nf, const float* __restrict__ WT,
    float* __restrict__ h0) {
    __shared__ float sNF[64 * 76];
    int nb = blockIdx.x * 64;
    int tid = threadIdx.x;
    for (int idx = tid; idx < 64 * F_INF; idx += 256) {
        int row = idx / F_INF, f = idx % F_INF;
        sNF[row * 76 + f] = nf[(size_t)nb * F_INF + idx];  // contiguous global read
    }
    __syncthreads();
    int tc = tid & 31;   // cols tc*4 .. +3 (of 128)
    int tn = tid >> 5;   // 0..7 -> nodes tn*8 .. +7
    int c0 = tc * 4;
    float acc[8][4];
    #pragma unroll
    for (int i = 0; i < 8; i++)
        #pragma unroll
        for (int j = 0; j < 4; j++) acc[i][j] = 0.f;
    for (int k = 0; k < F_INF; k++) {
        float4 w = *reinterpret_cast<const float4*>(&WT[k * D0 + c0]);
        #pragma unroll
        for (int i = 0; i < 8; i++) {
            float a = sNF[(tn * 8 + i) * 76 + k];
            acc[i][0] += a * w.x; acc[i][1] += a * w.y;
            acc[i][2] += a * w.z; acc[i][3] += a * w.w;
        }
    }
    #pragma unroll
    for (int i = 0; i < 8; i++) {
        float4 o = make_float4(acc[i][0], acc[i][1], acc[i][2], acc[i][3]);
        *reinterpret_cast<float4*>(&h0[(size_t)(nb + tn * 8 + i) * D0 + c0]) = o;
    }
}

// ---------- CSR gather: agg[i] = rsq_in[i] * sum_{s in N(i)} rsq_out[s]*x[s] ----------

template<int DIM>
__global__ __launch_bounds__(256) void k_gather(
    const float* __restrict__ x, const float* __restrict__ rsq_out,
    const float* __restrict__ rsq_in,
    const int* __restrict__ row_off, const int* __restrict__ csr_src,
    float* __restrict__ agg) {
    const int TPN = DIM / 4;   // threads per node
    int node = blockIdx.x * (256 / TPN) + threadIdx.x / TPN;
    int f = (threadIdx.x % TPN) * 4;
    int beg = row_off[node], end = row_off[node + 1];
    float ax = 0.f, ay = 0.f, az = 0.f, aw = 0.f;
    for (int e = beg; e < end; e++) {
        int s = csr_src[e];
        float sc = rsq_out[s];
        float4 v = *reinterpret_cast<const float4*>(&x[(size_t)s * DIM + f]);
        ax += v.x * sc; ay += v.y * sc; az += v.z * sc; aw += v.w * sc;
    }
    float si = rsq_in[node];
    float4 o = make_float4(ax * si, ay * si, az * si, aw * si);
    *reinterpret_cast<float4*>(&agg[(size_t)node * DIM + f]) = o;
}

// ---------- layer1: t1 = gelu(agg1 @ w1 + b1) + h0 @ rwT + rb ----------

__global__ __launch_bounds__(256) void k_layer1_gemm(
    const float* __restrict__ agg, const float* __restrict__ h0,
    const float* __restrict__ w1,   // [128][256] k-major
    const float* __restrict__ rwT,  // [128][256] k-major
    const float* __restrict__ b1, const float* __restrict__ rb,
    float* __restrict__ t1) {
    __shared__ float sA[64 * 132];
    __shared__ float sH[64 * 132];
    int nb = blockIdx.x * 64;
    int cb = blockIdx.y * 64;
    int tid = threadIdx.x;
    #pragma unroll
    for (int j = 0; j < 8; j++) {
        int idx = tid + j * 256;
        int row = idx >> 5;
        int k4 = (idx & 31) * 4;
        float4 a = *reinterpret_cast<const float4*>(&agg[(size_t)(nb + row) * D0 + k4]);
        float4 h = *reinterpret_cast<const float4*>(&h0[(size_t)(nb + row) * D0 + k4]);
        *reinterpret_cast<float4*>(&sA[row * 132 + k4]) = a;
        *reinterpret_cast<float4*>(&sH[row * 132 + k4]) = h;
    }
    __syncthreads();
    int tc = tid & 15, tn = tid >> 4;
    int c0 = cb + tc * 4;
    int r0 = tn * 4;
    float accG[4][4] = {{0.f}}, accR[4][4] = {{0.f}};
    for (int k = 0; k < D0; k++) {
        float4 w  = *reinterpret_cast<const float4*>(&w1[k * D1 + c0]);
        float4 rw = *reinterpret_cast<const float4*>(&rwT[k * D1 + c0]);
        #pragma unroll
        for (int i = 0; i < 4; i++) {
            float a = sA[(r0 + i) * 132 + k];
            float h = sH[(r0 + i) * 132 + k];
            accG[i][0] += a * w.x;  accG[i][1] += a * w.y;
            accG[i][2] += a * w.z;  accG[i][3] += a * w.w;
            accR[i][0] += h * rw.x; accR[i][1] += h * rw.y;
            accR[i][2] += h * rw.z; accR[i][3] += h * rw.w;
        }
    }
    float4 bb  = *reinterpret_cast<const float4*>(&b1[c0]);
    float4 rbb = *reinterpret_cast<const float4*>(&rb[c0]);
    #pragma unroll
    for (int i = 0; i < 4; i++) {
        float4 o;
        o.x = gelu_exact(accG[i][0] + bb.x) + accR[i][0] + rbb.x;
        o.y = gelu_exact(accG[i][1] + bb.y) + accR[i][1] + rbb.y;
        o.z = gelu_exact(accG[i][2] + bb.z) + accR[i][2] + rbb.z;
        o.w = gelu_exact(accG[i][3] + bb.w) + accR[i][3] + rbb.w;
        *reinterpret_cast<float4*>(&t1[(size_t)(nb + r0 + i) * D1 + c0]) = o;
    }
}

// ---------- layer2: t2 = gelu(agg2 @ w2 + b2) + h1 ----------

__global__ __launch_bounds__(256) void k_layer2_gemm(
    const float* __restrict__ agg,
    const float* __restrict__ w2,  // [256][256] k-major
    const float* __restrict__ b2,
    const float* __restrict__ h1, float* __restrict__ t2) {
    __shared__ float sA[64 * 260];
    int nb = blockIdx.x * 64, cb = blockIdx.y * 64, tid = threadIdx.x;
    #pragma unroll
    for (int j = 0; j < 16; j++) {
        int idx = tid + j * 256;
        int row = idx >> 6;
        int k4 = (idx & 63) * 4;
        float4 a = *reinterpret_cast<const float4*>(&agg[(size_t)(nb + row) * D1 + k4]);
        *reinterpret_cast<float4*>(&sA[row * 260 + k4]) = a;
    }
    __syncthreads();
    int tc = tid & 15, tn = tid >> 4;
    int c0 = cb + tc * 4, r0 = tn * 4;
    float acc[4][4] = {{0.f}};
    for (int k = 0; k < D1; k++) {
        float4 w = *reinterpret_cast<const float4*>(&w2[k * D1 + c0]);
        #pragma unroll
        for (int i = 0; i < 4; i++) {
            float a = sA[(r0 + i) * 260 + k];
            acc[i][0] += a * w.x; acc[i][1] += a * w.y;
            acc[i][2] += a * w.z; acc[i][3] += a * w.w;
        }
    }
    float4 bb = *reinterpret_cast<const float4*>(&b2[c0]);
    #pragma unroll
    for (int i = 0; i < 4; i++) {
        float4 hv = *reinterpret_cast<const float4*>(&h1[(size_t)(nb + r0 + i) * D1 + c0]);
        float4 o;
        o.x = gelu_exact(acc[i][0] + bb.x) + hv.x;
        o.y = gelu_exact(acc[i][1] + bb.y) + hv.y;
        o.z = gelu_exact(acc[i][2] + bb.z) + hv.z;
        o.w = gelu_exact(acc[i][3] + bb.w) + hv.w;
        *reinterpret_cast<float4*>(&t2[(size_t)(nb + r0 + i) * D1 + c0]) = o;
    }
}

// ---------- BatchNorm ----------

__global__ __launch_bounds__(256) void k_bn_stats(const float* __restrict__ x,
                                                  float* __restrict__ sums) {
    int col = threadIdx.x;        // 256 channels
    int base = blockIdx.x * 128;  // 128 nodes per block
    float s = 0.f, q = 0.f;
    for (int i = 0; i < 128; i++) {
        float v = x[(size_t)(base + i) * D1 + col];
        s += v; q += v * v;
    }
    atomicAdd(&sums[col], s);
    atomicAdd(&sums[D1 + col], q);
}

__global__ __launch_bounds__(256) void k_bn_apply(
    const float* __restrict__ x, const float* __restrict__ sums,
    const float* __restrict__ g, const float* __restrict__ b,
    float* __restrict__ y) {
    int idx = blockIdx.x * 256 + threadIdx.x;   // over N*D1/4 float4s
    int c4 = (idx & 63) * 4;
    float4 v  = *reinterpret_cast<const float4*>(&x[(size_t)idx * 4]);
    float4 sv = *reinterpret_cast<const float4*>(&sums[c4]);
    float4 qv = *reinterpret_cast<const float4*>(&sums[D1 + c4]);
    float4 gv = *reinterpret_cast<const float4*>(&g[c4]);
    float4 bv = *reinterpret_cast<const float4*>(&b[c4]);
    const float invN = 1.0f / (float)N_NODES;
    float4 o;
    {
        float m = sv.x * invN; float var = qv.x * invN - m * m;
        o.x = (v.x - m) * (1.0f / sqrtf(var + BN_EPS)) * gv.x + bv.x;
    }
    {
        float m = sv.y * invN; float var = qv.y * invN - m * m;
        o.y = (v.y - m) * (1.0f / sqrtf(var + BN_EPS)) * gv.y + bv.y;
    }
    {
        float m = sv.z * invN; float var = qv.z * invN - m * m;
        o.z = (v.z - m) * (1.0f / sqrtf(var + BN_EPS)) * gv.z + bv.z;
    }
    {
        float m = sv.w * invN; float var = qv.w * invN - m * m;
        o.w = (v.w - m) * (1.0f / sqrtf(var + BN_EPS)) * gv.w + bv.w;
    }
    *reinterpret_cast<float4*>(&y[(size_t)idx * 4]) = o;
}

// ---------- launch ----------

extern "C" void kernel_launch(void* const* d_in, const int* in_sizes, int n_in,
                              void* d_out, int out_size, void* d_ws, size_t ws_size,
                              hipStream_t stream) {
    const float* node_feats = (const float*)d_in[0];
    const float* W_init     = (const float*)d_in[1];
    const float* gcn_w1     = (const float*)d_in[2];
    const float* gcn_b1     = (const float*)d_in[3];
    const float* res_w1     = (const float*)d_in[4];
    const float* res_b1     = (const float*)d_in[5];
    const float* bn_g1      = (const float*)d_in[6];
    const float* bn_b1      = (const float*)d_in[7];
    const float* gcn_w2     = (const float*)d_in[8];
    const float* gcn_b2     = (const float*)d_in[9];
    const float* bn_g2      = (const float*)d_in[10];
    const float* bn_b2      = (const float*)d_in[11];
    const int*   edge_src   = (const int*)d_in[12];
    const int*   edge_dst   = (const int*)d_in[13];
    float* out = (float*)d_out;

    float* ws = (float*)d_ws;
    float* h0   = ws;                            // N*128
    float* agg1 = ws + (size_t)N_NODES * 128;    // N*128
    float* t1   = ws + (size_t)N_NODES * 256;    // N*256  (reused as agg2)
    float* h1   = ws + (size_t)N_NODES * 512;    // N*256
    float* t2   = ws;                            // reuse [0, N*256)
    float* agg2 = t1;
    float* rsq_out = ws + (size_t)N_NODES * 768;
    float* rsq_in  = rsq_out + N_NODES;
    int*   degi    = (int*)(rsq_in + N_NODES);      // 2N ints
    int*   cursor  = degi + 2 * N_NODES;            // N ints
    float* stats1  = (float*)(cursor + N_NODES);    // 512 floats
    float* stats2  = stats1 + 512;                  // 512 floats
    float* WT      = stats2 + 512;                  // 74*128
    float* rwT     = WT + F_INF * D0;               // 128*256
    int*   row_off = (int*)(rwT + D0 * D1);         // N+1 ints
    int*   csr_src = row_off + N_NODES + 2;         // E ints

    // zero: degi(2N) + cursor(N) ints, then stats (1024 floats)
    hipMemsetAsync(degi, 0, 3 * N_NODES * sizeof(int), stream);
    hipMemsetAsync(stats1, 0, 1024 * sizeof(float), stream);

    k_degrees<<<(E_EDGES + 255) / 256, 256, 0, stream>>>(edge_src, edge_dst, degi);
    k_rsq<<<(N_NODES + 255) / 256, 256, 0, stream>>>(degi, rsq_out, rsq_in);
    k_scan<<<1, 1024, 0, stream>>>(degi + N_NODES, row_off);
    k_fill<<<(E_EDGES + 255) / 256, 256, 0, stream>>>(edge_src, edge_dst, row_off, cursor, csr_src);

    k_transpose_winit<<<(F_INF * D0 + 255) / 256, 256, 0, stream>>>(W_init, WT);
    k_transpose_rw<<<(D0 * D1) / 256, 256, 0, stream>>>(res_w1, rwT);

    k_init_gemm<<<N_NODES / 64, 256, 0, stream>>>(node_feats, WT, h0);

    k_gather<128><<<N_NODES / 8, 256, 0, stream>>>(h0, rsq_out, rsq_in, row_off, csr_src, agg1);

    k_layer1_gemm<<<dim3(N_NODES / 64, 4), 256, 0, stream>>>(
        agg1, h0, gcn_w1, rwT, gcn_b1, res_b1, t1);

    k_bn_stats<<<N_NODES / 128, 256, 0, stream>>>(t1, stats1);
    k_bn_apply<<<(N_NODES * 64) / 256, 256, 0, stream>>>(t1, stats1, bn_g1, bn_b1, h1);

    k_gather<256><<<N_NODES / 4, 256, 0, stream>>>(h1, rsq_out, rsq_in, row_off, csr_src, agg2);

    k_layer2_gemm<<<dim3(N_NODES / 64, 4), 256, 0, stream>>>(
        agg2, gcn_w2, gcn_b2, h1, t2);

    k_bn_stats<<<N_NODES / 128, 256, 0, stream>>>(t2, stats2);
    k_bn_apply<<<(N_NODES * 64) / 256, 256, 0, stream>>>(t2, stats2, bn_g2, bn_b2, out);
}

// Round 3
// 292.983 us; speedup vs baseline: 5.6388x; 1.4435x over previous
//
#include <hip/hip_runtime.h>
#include <hip/hip_bf16.h>
#include <math.h>

#define N_NODES 32768
#define E_EDGES 262144
#define F_INF   74
#define D0      128
#define D1      256
#define BN_EPS  1e-5f
#define NBLK    512     // N_NODES / 64

typedef float f32x4 __attribute__((ext_vector_type(4)));
typedef short s16x8 __attribute__((ext_vector_type(8)));

__device__ __forceinline__ float b2f(ushort h) { return __uint_as_float(((unsigned)h) << 16); }
__device__ __forceinline__ ushort f2b(float f) {
    unsigned u = __float_as_uint(f);
    return (ushort)((u + 0x7FFFu + ((u >> 16) & 1u)) >> 16);
}
__device__ __forceinline__ float gelu_exact(float x) {
    return 0.5f * x * (1.0f + erff(x * 0.70710678118654752440f));
}

// ---------- graph prep ----------

__global__ void k_degrees(const int* __restrict__ src, const int* __restrict__ dst,
                          int* __restrict__ deg) {
    int e = blockIdx.x * 256 + threadIdx.x;
    if (e < E_EDGES) {
        atomicAdd(&deg[src[e]], 1);
        atomicAdd(&deg[N_NODES + dst[e]], 1);
    }
}

__global__ void k_rsq(const int* __restrict__ deg, float* __restrict__ rsq_out,
                      float* __restrict__ rsq_in) {
    int i = blockIdx.x * 256 + threadIdx.x;
    if (i < N_NODES) {
        int d_o = deg[i];           if (d_o < 1) d_o = 1;
        int d_i = deg[N_NODES + i]; if (d_i < 1) d_i = 1;
        rsq_out[i] = 1.0f / sqrtf((float)d_o);
        rsq_in[i]  = 1.0f / sqrtf((float)d_i);
    }
}

__global__ __launch_bounds__(1024) void k_scan(const int* __restrict__ deg_in,
                                               int* __restrict__ row_off) {
    __shared__ int part[1024];
    int t = threadIdx.x;
    int base = t * 32;
    int loc[32];
    int s = 0;
    #pragma unroll
    for (int i = 0; i < 32; i++) { loc[i] = s; s += deg_in[base + i]; }
    part[t] = s;
    __syncthreads();
    for (int off = 1; off < 1024; off <<= 1) {
        int v = 0;
        if (t >= off) v = part[t - off];
        __syncthreads();
        if (t >= off) part[t] += v;
        __syncthreads();
    }
    int pre = (t == 0) ? 0 : part[t - 1];
    #pragma unroll
    for (int i = 0; i < 32; i++) row_off[base + i] = pre + loc[i];
    if (t == 1023) row_off[N_NODES] = part[1023];
}

__global__ void k_fill(const int* __restrict__ src, const int* __restrict__ dst,
                       const int* __restrict__ row_off, int* __restrict__ cursor,
                       int* __restrict__ csr_src) {
    int e = blockIdx.x * 256 + threadIdx.x;
    if (e < E_EDGES) {
        int d = dst[e];
        int slot = atomicAdd(&cursor[d], 1);
        csr_src[row_off[d] + slot] = src[e];
    }
}

// ---------- weight prep ----------

__global__ void k_transpose_winit(const float* __restrict__ W, float* __restrict__ WT) {
    int idx = blockIdx.x * 256 + threadIdx.x;
    if (idx < F_INF * D0) {
        int f = idx / D0, c = idx % D0;
        WT[f * D0 + c] = W[c * F_INF + f];
    }
}

// WB1[n][k] = bf16(gcn_w1[k][n])  (gcn_w1 is [128][256]); RWB[n][k] = bf16(res_w1[n][k])
__global__ void k_prep_l1(const float* __restrict__ w1, const float* __restrict__ rw,
                          ushort* __restrict__ WB1, ushort* __restrict__ RWB) {
    int idx = blockIdx.x * 256 + threadIdx.x;   // 256*128
    int n = idx >> 7, k = idx & 127;
    WB1[idx] = f2b(w1[k * D1 + n]);
    RWB[idx] = f2b(rw[idx]);
}

// WB2[n][k] = bf16(gcn_w2[k][n])  (gcn_w2 is [256][256])
__global__ void k_prep_w2(const float* __restrict__ w2, ushort* __restrict__ WB2) {
    int idx = blockIdx.x * 256 + threadIdx.x;   // 256*256
    int n = idx >> 8, k = idx & 255;
    WB2[idx] = f2b(w2[k * D1 + n]);
}

// ---------- init GEMM: h0 = nf @ W_init^T  -> bf16 ----------

__global__ __launch_bounds__(256) void k_init_gemm(
    const float* __restrict__ nf, const float* __restrict__ WT,
    ushort* __restrict__ h0) {
    __shared__ float sNF[64 * 76];
    int nb = blockIdx.x * 64;
    int tid = threadIdx.x;
    for (int idx = tid; idx < 64 * F_INF; idx += 256) {
        int row = idx / F_INF, f = idx % F_INF;
        sNF[row * 76 + f] = nf[(size_t)nb * F_INF + idx];
    }
    __syncthreads();
    int tc = tid & 31;
    int tn = tid >> 5;
    int c0 = tc * 4;
    float acc[8][4];
    #pragma unroll
    for (int i = 0; i < 8; i++)
        #pragma unroll
        for (int j = 0; j < 4; j++) acc[i][j] = 0.f;
    for (int k = 0; k < F_INF; k++) {
        float4 w = *reinterpret_cast<const float4*>(&WT[k * D0 + c0]);
        #pragma unroll
        for (int i = 0; i < 8; i++) {
            float a = sNF[(tn * 8 + i) * 76 + k];
            acc[i][0] += a * w.x; acc[i][1] += a * w.y;
            acc[i][2] += a * w.z; acc[i][3] += a * w.w;
        }
    }
    #pragma unroll
    for (int i = 0; i < 8; i++) {
        ushort4 o;
        o.x = f2b(acc[i][0]); o.y = f2b(acc[i][1]);
        o.z = f2b(acc[i][2]); o.w = f2b(acc[i][3]);
        *reinterpret_cast<ushort4*>(&h0[(size_t)(nb + tn * 8 + i) * D0 + c0]) = o;
    }
}

// ---------- gather1: agg1 = rsq_in * sum rsq_out[s]*h0[s]   (bf16 in/out) ----------

__global__ __launch_bounds__(256) void k_gather1(
    const ushort* __restrict__ x, const float* __restrict__ rsq_out,
    const float* __restrict__ rsq_in,
    const int* __restrict__ row_off, const int* __restrict__ csr_src,
    ushort* __restrict__ agg) {
    int tid = threadIdx.x;
    int node = blockIdx.x * 16 + (tid >> 4);
    int f = (tid & 15) * 8;
    int beg = row_off[node], end = row_off[node + 1];
    float a[8];
    #pragma unroll
    for (int j = 0; j < 8; j++) a[j] = 0.f;
    for (int e = beg; e < end; e++) {
        int s = csr_src[e];
        float sc = rsq_out[s];
        s16x8 v = *reinterpret_cast<const s16x8*>(&x[(size_t)s * D0 + f]);
        #pragma unroll
        for (int j = 0; j < 8; j++) a[j] += b2f((ushort)v[j]) * sc;
    }
    float si = rsq_in[node];
    s16x8 o;
    #pragma unroll
    for (int j = 0; j < 8; j++) o[j] = (short)f2b(a[j] * si);
    *reinterpret_cast<s16x8*>(&agg[(size_t)node * D0 + f]) = o;
}

// ---------- gather2: agg2 = rsq_in * sum rsq_out[s]*(sc1*t1[s]+sh1)  (bf16) ----------

__global__ __launch_bounds__(256) void k_gather2(
    const ushort* __restrict__ t1, const float* __restrict__ sc1,
    const float* __restrict__ sh1,
    const float* __restrict__ rsq_out, const float* __restrict__ rsq_in,
    const int* __restrict__ row_off, const int* __restrict__ csr_src,
    ushort* __restrict__ agg) {
    int tid = threadIdx.x;
    int node = blockIdx.x * 8 + (tid >> 5);
    int f = (tid & 31) * 8;
    float A[8], B[8];
    #pragma unroll
    for (int j = 0; j < 8; j++) { A[j] = sc1[f + j]; B[j] = sh1[f + j]; }
    int beg = row_off[node], end = row_off[node + 1];
    float a[8];
    #pragma unroll
    for (int j = 0; j < 8; j++) a[j] = 0.f;
    for (int e = beg; e < end; e++) {
        int s = csr_src[e];
        float sc = rsq_out[s];
        s16x8 v = *reinterpret_cast<const s16x8*>(&t1[(size_t)s * D1 + f]);
        #pragma unroll
        for (int j = 0; j < 8; j++) a[j] += fmaf(b2f((ushort)v[j]), A[j], B[j]) * sc;
    }
    float si = rsq_in[node];
    s16x8 o;
    #pragma unroll
    for (int j = 0; j < 8; j++) o[j] = (short)f2b(a[j] * si);
    *reinterpret_cast<s16x8*>(&agg[(size_t)node * D1 + f]) = o;
}

// ---------- layer1 MFMA: t1 = gelu(agg1@w1 + b1) + h0@rw^T + rb, + BN partials ----------

__global__ __launch_bounds__(256) void k_layer1(
    const ushort* __restrict__ aggB, const ushort* __restrict__ h0B,
    const ushort* __restrict__ WB1, const ushort* __restrict__ RWB,
    const float* __restrict__ b1, const float* __restrict__ rb,
    ushort* __restrict__ t1B, float* __restrict__ partials) {
    __shared__ float lsum[512];
    int tid = threadIdx.x;
    for (int i = tid; i < 512; i += 256) lsum[i] = 0.f;
    __syncthreads();
    int w = tid >> 6, lane = tid & 63, m = lane & 15, g4 = lane >> 4;
    int rb0 = blockIdx.x * 64 + w * 16;
    f32x4 accG[16], accR[16];
    #pragma unroll
    for (int i = 0; i < 16; i++) {
        accG[i] = (f32x4){0.f, 0.f, 0.f, 0.f};
        accR[i] = (f32x4){0.f, 0.f, 0.f, 0.f};
    }
    const ushort* pa = &aggB[(size_t)(rb0 + m) * D0 + g4 * 8];
    const ushort* ph = &h0B[(size_t)(rb0 + m) * D0 + g4 * 8];
    for (int k0 = 0; k0 < D0; k0 += 32) {
        s16x8 aA = *reinterpret_cast<const s16x8*>(pa + k0);
        s16x8 aH = *reinterpret_cast<const s16x8*>(ph + k0);
        #pragma unroll
        for (int nt = 0; nt < 16; nt++) {
            s16x8 bG = *reinterpret_cast<const s16x8*>(&WB1[(size_t)(nt * 16 + m) * D0 + k0 + g4 * 8]);
            s16x8 bR = *reinterpret_cast<const s16x8*>(&RWB[(size_t)(nt * 16 + m) * D0 + k0 + g4 * 8]);
            accG[nt] = __builtin_amdgcn_mfma_f32_16x16x32_bf16(aA, bG, accG[nt], 0, 0, 0);
            accR[nt] = __builtin_amdgcn_mfma_f32_16x16x32_bf16(aH, bR, accR[nt], 0, 0, 0);
        }
    }
    #pragma unroll
    for (int nt = 0; nt < 16; nt++) {
        int col = nt * 16 + m;
        float bgv = b1[col], brv = rb[col];
        float ps = 0.f, pq = 0.f;
        #pragma unroll
        for (int r = 0; r < 4; r++) {
            int row = rb0 + g4 * 4 + r;
            float v = gelu_exact(accG[nt][r] + bgv) + accR[nt][r] + brv;
            t1B[(size_t)row * D1 + col] = f2b(v);
            ps += v; pq += v * v;
        }
        ps += __shfl_xor(ps, 16); ps += __shfl_xor(ps, 32);
        pq += __shfl_xor(pq, 16); pq += __shfl_xor(pq, 32);
        if (g4 == 0) {
            atomicAdd(&lsum[col], ps);
            atomicAdd(&lsum[256 + col], pq);
        }
    }
    __syncthreads();
    for (int i = tid; i < 512; i += 256) partials[(size_t)blockIdx.x * 512 + i] = lsum[i];
}

// ---------- layer2 MFMA: t2 = gelu(agg2@w2 + b2) + (sc1*t1+sh1), + BN partials ----------

__global__ __launch_bounds__(256) void k_layer2(
    const ushort* __restrict__ aggB, const ushort* __restrict__ WB2,
    const float* __restrict__ b2,
    const ushort* __restrict__ t1B, const float* __restrict__ sc1,
    const float* __restrict__ sh1,
    ushort* __restrict__ t2B, float* __restrict__ partials) {
    __shared__ float lsum[512];
    int tid = threadIdx.x;
    for (int i = tid; i < 512; i += 256) lsum[i] = 0.f;
    __syncthreads();
    int w = tid >> 6, lane = tid & 63, m = lane & 15, g4 = lane >> 4;
    int rb0 = blockIdx.x * 64 + w * 16;
    f32x4 acc[16];
    #pragma unroll
    for (int i = 0; i < 16; i++) acc[i] = (f32x4){0.f, 0.f, 0.f, 0.f};
    const ushort* pa = &aggB[(size_t)(rb0 + m) * D1 + g4 * 8];
    for (int k0 = 0; k0 < D1; k0 += 32) {
        s16x8 aA = *reinterpret_cast<const s16x8*>(pa + k0);
        #pragma unroll
        for (int nt = 0; nt < 16; nt++) {
            s16x8 bG = *reinterpret_cast<const s16x8*>(&WB2[(size_t)(nt * 16 + m) * D1 + k0 + g4 * 8]);
            acc[nt] = __builtin_amdgcn_mfma_f32_16x16x32_bf16(aA, bG, acc[nt], 0, 0, 0);
        }
    }
    #pragma unroll
    for (int nt = 0; nt < 16; nt++) {
        int col = nt * 16 + m;
        float bgv = b2[col];
        float a1 = sc1[col], s1 = sh1[col];
        float ps = 0.f, pq = 0.f;
        #pragma unroll
        for (int r = 0; r < 4; r++) {
            int row = rb0 + g4 * 4 + r;
            float h1v = fmaf(b2f(t1B[(size_t)row * D1 + col]), a1, s1);
            float v = gelu_exact(acc[nt][r] + bgv) + h1v;
            t2B[(size_t)row * D1 + col] = f2b(v);
            ps += v; pq += v * v;
        }
        ps += __shfl_xor(ps, 16); ps += __shfl_xor(ps, 32);
        pq += __shfl_xor(pq, 16); pq += __shfl_xor(pq, 32);
        if (g4 == 0) {
            atomicAdd(&lsum[col], ps);
            atomicAdd(&lsum[256 + col], pq);
        }
    }
    __syncthreads();
    for (int i = tid; i < 512; i += 256) partials[(size_t)blockIdx.x * 512 + i] = lsum[i];
}

// ---------- BN reduce: partials -> per-channel scale/shift ----------

__global__ __launch_bounds__(512) void k_reduce(
    const float* __restrict__ partials, const float* __restrict__ g,
    const float* __restrict__ b, float* __restrict__ sc, float* __restrict__ sh) {
    __shared__ float L[512];
    int j = threadIdx.x;
    float s = 0.f;
    for (int bb = 0; bb < NBLK; bb++) s += partials[(size_t)bb * 512 + j];
    L[j] = s;
    __syncthreads();
    if (j < 256) {
        float m = L[j] * (1.0f / (float)N_NODES);
        float var = L[j + 256] * (1.0f / (float)N_NODES) - m * m;
        float a = g[j] / sqrtf(var + BN_EPS);
        sc[j] = a;
        sh[j] = b[j] - m * a;
    }
}

// ---------- final BN apply: out = sc2*t2 + sh2  (fp32 out) ----------

__global__ __launch_bounds__(256) void k_apply(
    const ushort* __restrict__ t2B, const float* __restrict__ sc,
    const float* __restrict__ sh, float* __restrict__ out) {
    int idx = blockIdx.x * 256 + threadIdx.x;
    size_t base = (size_t)idx * 8;
    int c = (int)(base & 255);
    s16x8 v = *reinterpret_cast<const s16x8*>(&t2B[base]);
    float4 o0, o1;
    o0.x = fmaf(b2f((ushort)v[0]), sc[c + 0], sh[c + 0]);
    o0.y = fmaf(b2f((ushort)v[1]), sc[c + 1], sh[c + 1]);
    o0.z = fmaf(b2f((ushort)v[2]), sc[c + 2], sh[c + 2]);
    o0.w = fmaf(b2f((ushort)v[3]), sc[c + 3], sh[c + 3]);
    o1.x = fmaf(b2f((ushort)v[4]), sc[c + 4], sh[c + 4]);
    o1.y = fmaf(b2f((ushort)v[5]), sc[c + 5], sh[c + 5]);
    o1.z = fmaf(b2f((ushort)v[6]), sc[c + 6], sh[c + 6]);
    o1.w = fmaf(b2f((ushort)v[7]), sc[c + 7], sh[c + 7]);
    *reinterpret_cast<float4*>(&out[base]) = o0;
    *reinterpret_cast<float4*>(&out[base + 4]) = o1;
}

// ---------- launch ----------

static inline size_t align256(size_t x) { return (x + 255) & ~(size_t)255; }

extern "C" void kernel_launch(void* const* d_in, const int* in_sizes, int n_in,
                              void* d_out, int out_size, void* d_ws, size_t ws_size,
                              hipStream_t stream) {
    const float* node_feats = (const float*)d_in[0];
    const float* W_init     = (const float*)d_in[1];
    const float* gcn_w1     = (const float*)d_in[2];
    const float* gcn_b1     = (const float*)d_in[3];
    const float* res_w1     = (const float*)d_in[4];
    const float* res_b1     = (const float*)d_in[5];
    const float* bn_g1      = (const float*)d_in[6];
    const float* bn_b1      = (const float*)d_in[7];
    const float* gcn_w2     = (const float*)d_in[8];
    const float* gcn_b2     = (const float*)d_in[9];
    const float* bn_g2      = (const float*)d_in[10];
    const float* bn_b2      = (const float*)d_in[11];
    const int*   edge_src   = (const int*)d_in[12];
    const int*   edge_dst   = (const int*)d_in[13];
    float* out = (float*)d_out;

    char* p = (char*)d_ws;
    size_t off = 0;
    auto take = [&](size_t bytes) { void* r = p + off; off += align256(bytes); return r; };

    ushort* h0B   = (ushort*)take((size_t)N_NODES * D0 * 2);
    ushort* agg1B = (ushort*)take((size_t)N_NODES * D0 * 2);
    ushort* t1B   = (ushort*)take((size_t)N_NODES * D1 * 2);
    ushort* agg2B = (ushort*)take((size_t)N_NODES * D1 * 2);
    ushort* t2B   = (ushort*)take((size_t)N_NODES * D1 * 2);
    float*  WT    = (float*)take((size_t)F_INF * D0 * 4);
    ushort* WB1   = (ushort*)take((size_t)D1 * D0 * 2);
    ushort* RWB   = (ushort*)take((size_t)D1 * D0 * 2);
    ushort* WB2   = (ushort*)take((size_t)D1 * D1 * 2);
    float*  part1 = (float*)take((size_t)NBLK * 512 * 4);
    float*  part2 = (float*)take((size_t)NBLK * 512 * 4);
    float*  sc1   = (float*)take(256 * 4);
    float*  sh1   = (float*)take(256 * 4);
    float*  sc2   = (float*)take(256 * 4);
    float*  sh2   = (float*)take(256 * 4);
    float*  rsq_out = (float*)take((size_t)N_NODES * 4);
    float*  rsq_in  = (float*)take((size_t)N_NODES * 4);
    int*    degi    = (int*)take((size_t)2 * N_NODES * 4);
    int*    cursor  = (int*)take((size_t)N_NODES * 4);
    int*    row_off = (int*)take((size_t)(N_NODES + 2) * 4);
    int*    csr_src = (int*)take((size_t)E_EDGES * 4);

    // degi + cursor are contiguous (modulo 256B pad) — zero them separately
    hipMemsetAsync(degi, 0, (size_t)2 * N_NODES * 4, stream);
    hipMemsetAsync(cursor, 0, (size_t)N_NODES * 4, stream);

    k_degrees<<<(E_EDGES + 255) / 256, 256, 0, stream>>>(edge_src, edge_dst, degi);
    k_rsq<<<(N_NODES + 255) / 256, 256, 0, stream>>>(degi, rsq_out, rsq_in);
    k_scan<<<1, 1024, 0, stream>>>(degi + N_NODES, row_off);
    k_fill<<<(E_EDGES + 255) / 256, 256, 0, stream>>>(edge_src, edge_dst, row_off, cursor, csr_src);

    k_transpose_winit<<<(F_INF * D0 + 255) / 256, 256, 0, stream>>>(W_init, WT);
    k_prep_l1<<<(D1 * D0) / 256, 256, 0, stream>>>(gcn_w1, res_w1, WB1, RWB);
    k_prep_w2<<<(D1 * D1) / 256, 256, 0, stream>>>(gcn_w2, WB2);

    k_init_gemm<<<N_NODES / 64, 256, 0, stream>>>(node_feats, WT, h0B);

    k_gather1<<<N_NODES / 16, 256, 0, stream>>>(h0B, rsq_out, rsq_in, row_off, csr_src, agg1B);

    k_layer1<<<NBLK, 256, 0, stream>>>(agg1B, h0B, WB1, RWB, gcn_b1, res_b1, t1B, part1);
    k_reduce<<<1, 512, 0, stream>>>(part1, bn_g1, bn_b1, sc1, sh1);

    k_gather2<<<N_NODES / 8, 256, 0, stream>>>(t1B, sc1, sh1, rsq_out, rsq_in, row_off, csr_src, agg2B);

    k_layer2<<<NBLK, 256, 0, stream>>>(agg2B, WB2, gcn_b2, t1B, sc1, sh1, t2B, part2);
    k_reduce<<<1, 512, 0, stream>>>(part2, bn_g2, bn_b2, sc2, sh2);

    k_apply<<<(N_NODES * D1 / 8) / 256, 256, 0, stream>>>(t2B, sc2, sh2, out);
}

// Round 4
// 247.333 us; speedup vs baseline: 6.6796x; 1.1846x over previous
//
#include <hip/hip_runtime.h>
#include <hip/hip_bf16.h>
#include <math.h>

#define N_NODES 32768
#define E_EDGES 262144
#define F_INF   74
#define D0      128
#define D1      256
#define BN_EPS  1e-5f
#define NBLK    512     // row blocks (N_NODES / 64)

typedef float f32x4 __attribute__((ext_vector_type(4)));
typedef short s16x8 __attribute__((ext_vector_type(8)));

__device__ __forceinline__ float b2f(ushort h) { return __uint_as_float(((unsigned)h) << 16); }
__device__ __forceinline__ ushort f2b(float f) {
    unsigned u = __float_as_uint(f);
    return (ushort)((u + 0x7FFFu + ((u >> 16) & 1u)) >> 16);
}
__device__ __forceinline__ float gelu_exact(float x) {
    return 0.5f * x * (1.0f + erff(x * 0.70710678118654752440f));
}

// ---------- graph prep ----------

__global__ void k_degrees(const int* __restrict__ src, const int* __restrict__ dst,
                          int* __restrict__ deg) {
    int e = blockIdx.x * 256 + threadIdx.x;
    if (e < E_EDGES) {
        atomicAdd(&deg[src[e]], 1);
        atomicAdd(&deg[N_NODES + dst[e]], 1);
    }
}

__global__ void k_rsq(const int* __restrict__ deg, float* __restrict__ rsq_out,
                      float* __restrict__ rsq_in) {
    int i = blockIdx.x * 256 + threadIdx.x;
    if (i < N_NODES) {
        int d_o = deg[i];           if (d_o < 1) d_o = 1;
        int d_i = deg[N_NODES + i]; if (d_i < 1) d_i = 1;
        rsq_out[i] = 1.0f / sqrtf((float)d_o);
        rsq_in[i]  = 1.0f / sqrtf((float)d_i);
    }
}

__global__ __launch_bounds__(1024) void k_scan(const int* __restrict__ deg_in,
                                               int* __restrict__ row_off) {
    __shared__ int part[1024];
    int t = threadIdx.x;
    int base = t * 32;
    int loc[32];
    int s = 0;
    #pragma unroll
    for (int i = 0; i < 32; i++) { loc[i] = s; s += deg_in[base + i]; }
    part[t] = s;
    __syncthreads();
    for (int off = 1; off < 1024; off <<= 1) {
        int v = 0;
        if (t >= off) v = part[t - off];
        __syncthreads();
        if (t >= off) part[t] += v;
        __syncthreads();
    }
    int pre = (t == 0) ? 0 : part[t - 1];
    #pragma unroll
    for (int i = 0; i < 32; i++) row_off[base + i] = pre + loc[i];
    if (t == 1023) row_off[N_NODES] = part[1023];
}

__global__ void k_fill(const int* __restrict__ src, const int* __restrict__ dst,
                       const int* __restrict__ row_off, int* __restrict__ cursor,
                       int* __restrict__ csr_src) {
    int e = blockIdx.x * 256 + threadIdx.x;
    if (e < E_EDGES) {
        int d = dst[e];
        int slot = atomicAdd(&cursor[d], 1);
        csr_src[row_off[d] + slot] = src[e];
    }
}

// ---------- weight prep ----------

__global__ void k_transpose_winit(const float* __restrict__ W, float* __restrict__ WT) {
    int idx = blockIdx.x * 256 + threadIdx.x;
    if (idx < F_INF * D0) {
        int f = idx / D0, c = idx % D0;
        WT[f * D0 + c] = W[c * F_INF + f];
    }
}

// WB1[n][k] = bf16(gcn_w1[k][n]); RWB[n][k] = bf16(res_w1[n][k])
__global__ void k_prep_l1(const float* __restrict__ w1, const float* __restrict__ rw,
                          ushort* __restrict__ WB1, ushort* __restrict__ RWB) {
    int idx = blockIdx.x * 256 + threadIdx.x;   // 256*128
    int n = idx >> 7, k = idx & 127;
    WB1[idx] = f2b(w1[k * D1 + n]);
    RWB[idx] = f2b(rw[idx]);
}

// WB2[n][k] = bf16(gcn_w2[k][n])
__global__ void k_prep_w2(const float* __restrict__ w2, ushort* __restrict__ WB2) {
    int idx = blockIdx.x * 256 + threadIdx.x;   // 256*256
    int n = idx >> 8, k = idx & 255;
    WB2[idx] = f2b(w2[k * D1 + n]);
}

// ---------- init GEMM: h0 = nf @ W_init^T  -> bf16 ----------

__global__ __launch_bounds__(256) void k_init_gemm(
    const float* __restrict__ nf, const float* __restrict__ WT,
    ushort* __restrict__ h0) {
    __shared__ float sNF[64 * 76];
    int nb = blockIdx.x * 64;
    int tid = threadIdx.x;
    for (int idx = tid; idx < 64 * F_INF; idx += 256) {
        int row = idx / F_INF, f = idx % F_INF;
        sNF[row * 76 + f] = nf[(size_t)nb * F_INF + idx];
    }
    __syncthreads();
    int tc = tid & 31;
    int tn = tid >> 5;
    int c0 = tc * 4;
    float acc[8][4];
    #pragma unroll
    for (int i = 0; i < 8; i++)
        #pragma unroll
        for (int j = 0; j < 4; j++) acc[i][j] = 0.f;
    for (int k = 0; k < F_INF; k++) {
        float4 w = *reinterpret_cast<const float4*>(&WT[k * D0 + c0]);
        #pragma unroll
        for (int i = 0; i < 8; i++) {
            float a = sNF[(tn * 8 + i) * 76 + k];
            acc[i][0] += a * w.x; acc[i][1] += a * w.y;
            acc[i][2] += a * w.z; acc[i][3] += a * w.w;
        }
    }
    #pragma unroll
    for (int i = 0; i < 8; i++) {
        ushort4 o;
        o.x = f2b(acc[i][0]); o.y = f2b(acc[i][1]);
        o.z = f2b(acc[i][2]); o.w = f2b(acc[i][3]);
        *reinterpret_cast<ushort4*>(&h0[(size_t)(nb + tn * 8 + i) * D0 + c0]) = o;
    }
}

// ---------- gather1: agg1 = rsq_in * sum rsq_out[s]*h0[s]   (bf16 in/out) ----------

__global__ __launch_bounds__(256) void k_gather1(
    const ushort* __restrict__ x, const float* __restrict__ rsq_out,
    const float* __restrict__ rsq_in,
    const int* __restrict__ row_off, const int* __restrict__ csr_src,
    ushort* __restrict__ agg) {
    int tid = threadIdx.x;
    int node = blockIdx.x * 16 + (tid >> 4);
    int f = (tid & 15) * 8;
    int beg = row_off[node], end = row_off[node + 1];
    float a[8];
    #pragma unroll
    for (int j = 0; j < 8; j++) a[j] = 0.f;
    for (int e = beg; e < end; e++) {
        int s = csr_src[e];
        float sc = rsq_out[s];
        s16x8 v = *reinterpret_cast<const s16x8*>(&x[(size_t)s * D0 + f]);
        #pragma unroll
        for (int j = 0; j < 8; j++) a[j] += b2f((ushort)v[j]) * sc;
    }
    float si = rsq_in[node];
    s16x8 o;
    #pragma unroll
    for (int j = 0; j < 8; j++) o[j] = (short)f2b(a[j] * si);
    *reinterpret_cast<s16x8*>(&agg[(size_t)node * D0 + f]) = o;
}

// ---------- gather2: agg2 = rsq_in * sum rsq_out[s]*(sc1*t1[s]+sh1)  (bf16) ----------

__global__ __launch_bounds__(256) void k_gather2(
    const ushort* __restrict__ t1, const float* __restrict__ sc1,
    const float* __restrict__ sh1,
    const float* __restrict__ rsq_out, const float* __restrict__ rsq_in,
    const int* __restrict__ row_off, const int* __restrict__ csr_src,
    ushort* __restrict__ agg) {
    int tid = threadIdx.x;
    int node = blockIdx.x * 8 + (tid >> 5);
    int f = (tid & 31) * 8;
    float A[8], B[8];
    #pragma unroll
    for (int j = 0; j < 8; j++) { A[j] = sc1[f + j]; B[j] = sh1[f + j]; }
    int beg = row_off[node], end = row_off[node + 1];
    float a[8];
    #pragma unroll
    for (int j = 0; j < 8; j++) a[j] = 0.f;
    for (int e = beg; e < end; e++) {
        int s = csr_src[e];
        float sc = rsq_out[s];
        s16x8 v = *reinterpret_cast<const s16x8*>(&t1[(size_t)s * D1 + f]);
        #pragma unroll
        for (int j = 0; j < 8; j++) a[j] += fmaf(b2f((ushort)v[j]), A[j], B[j]) * sc;
    }
    float si = rsq_in[node];
    s16x8 o;
    #pragma unroll
    for (int j = 0; j < 8; j++) o[j] = (short)f2b(a[j] * si);
    *reinterpret_cast<s16x8*>(&agg[(size_t)node * D1 + f]) = o;
}

// ---------- layer1 MFMA, B-in-registers ----------
// grid (NBLK, 2), 256 thr = 4 waves; wave w owns cols by*128 + w*32 .. +31.
// Each block streams 64 rows (4 row-tiles of 16).

__global__ __launch_bounds__(256) void k_layer1(
    const ushort* __restrict__ aggB, const ushort* __restrict__ h0B,
    const ushort* __restrict__ WB1, const ushort* __restrict__ RWB,
    const float* __restrict__ b1, const float* __restrict__ rb,
    ushort* __restrict__ t1B, float* __restrict__ partials) {
    int tid = threadIdx.x;
    int w = tid >> 6, lane = tid & 63, m = lane & 15, g4 = lane >> 4;
    int cb = blockIdx.y * 128 + w * 32;
    s16x8 BG[2][4], BR[2][4];
    #pragma unroll
    for (int nt = 0; nt < 2; nt++)
        #pragma unroll
        for (int j = 0; j < 4; j++) {
            BG[nt][j] = *reinterpret_cast<const s16x8*>(&WB1[(size_t)(cb + nt * 16 + m) * D0 + j * 32 + g4 * 8]);
            BR[nt][j] = *reinterpret_cast<const s16x8*>(&RWB[(size_t)(cb + nt * 16 + m) * D0 + j * 32 + g4 * 8]);
        }
    float bg[2], brv[2];
    #pragma unroll
    for (int nt = 0; nt < 2; nt++) {
        bg[nt]  = b1[cb + nt * 16 + m];
        brv[nt] = rb[cb + nt * 16 + m];
    }
    int rbase = blockIdx.x * 64;
    float ps[2] = {0.f, 0.f}, pq[2] = {0.f, 0.f};
    #pragma unroll
    for (int rt = 0; rt < 4; rt++) {
        int r0 = rbase + rt * 16;
        s16x8 aA[4], aH[4];
        #pragma unroll
        for (int j = 0; j < 4; j++) {
            aA[j] = *reinterpret_cast<const s16x8*>(&aggB[(size_t)(r0 + m) * D0 + j * 32 + g4 * 8]);
            aH[j] = *reinterpret_cast<const s16x8*>(&h0B[(size_t)(r0 + m) * D0 + j * 32 + g4 * 8]);
        }
        f32x4 accG[2], accR[2];
        #pragma unroll
        for (int nt = 0; nt < 2; nt++) {
            accG[nt] = (f32x4){0.f, 0.f, 0.f, 0.f};
            accR[nt] = (f32x4){0.f, 0.f, 0.f, 0.f};
        }
        #pragma unroll
        for (int j = 0; j < 4; j++)
            #pragma unroll
            for (int nt = 0; nt < 2; nt++) {
                accG[nt] = __builtin_amdgcn_mfma_f32_16x16x32_bf16(aA[j], BG[nt][j], accG[nt], 0, 0, 0);
                accR[nt] = __builtin_amdgcn_mfma_f32_16x16x32_bf16(aH[j], BR[nt][j], accR[nt], 0, 0, 0);
            }
        #pragma unroll
        for (int nt = 0; nt < 2; nt++) {
            int col = cb + nt * 16 + m;
            #pragma unroll
            for (int r = 0; r < 4; r++) {
                int row = r0 + g4 * 4 + r;
                float v = gelu_exact(accG[nt][r] + bg[nt]) + accR[nt][r] + brv[nt];
                t1B[(size_t)row * D1 + col] = f2b(v);
                ps[nt] += v; pq[nt] += v * v;
            }
        }
    }
    #pragma unroll
    for (int nt = 0; nt < 2; nt++) {
        float s = ps[nt], q = pq[nt];
        s += __shfl_xor(s, 16); s += __shfl_xor(s, 32);
        q += __shfl_xor(q, 16); q += __shfl_xor(q, 32);
        if (g4 == 0) {
            int col = cb + nt * 16 + m;
            partials[(size_t)blockIdx.x * 512 + col] = s;
            partials[(size_t)blockIdx.x * 512 + 256 + col] = q;
        }
    }
}

// ---------- layer2 MFMA, B-in-registers: t2 = gelu(agg2@w2+b2) + (sc1*t1+sh1) ----------

__global__ __launch_bounds__(256) void k_layer2(
    const ushort* __restrict__ aggB, const ushort* __restrict__ WB2,
    const float* __restrict__ b2,
    const ushort* __restrict__ t1B, const float* __restrict__ sc1,
    const float* __restrict__ sh1,
    ushort* __restrict__ t2B, float* __restrict__ partials) {
    int tid = threadIdx.x;
    int w = tid >> 6, lane = tid & 63, m = lane & 15, g4 = lane >> 4;
    int cb = blockIdx.y * 128 + w * 32;
    s16x8 BG[2][8];
    #pragma unroll
    for (int nt = 0; nt < 2; nt++)
        #pragma unroll
        for (int j = 0; j < 8; j++)
            BG[nt][j] = *reinterpret_cast<const s16x8*>(&WB2[(size_t)(cb + nt * 16 + m) * D1 + j * 32 + g4 * 8]);
    float bg[2], a1[2], s1[2];
    #pragma unroll
    for (int nt = 0; nt < 2; nt++) {
        int col = cb + nt * 16 + m;
        bg[nt] = b2[col]; a1[nt] = sc1[col]; s1[nt] = sh1[col];
    }
    int rbase = blockIdx.x * 64;
    float ps[2] = {0.f, 0.f}, pq[2] = {0.f, 0.f};
    #pragma unroll
    for (int rt = 0; rt < 4; rt++) {
        int r0 = rbase + rt * 16;
        s16x8 aA[8];
        #pragma unroll
        for (int j = 0; j < 8; j++)
            aA[j] = *reinterpret_cast<const s16x8*>(&aggB[(size_t)(r0 + m) * D1 + j * 32 + g4 * 8]);
        f32x4 acc[2];
        #pragma unroll
        for (int nt = 0; nt < 2; nt++) acc[nt] = (f32x4){0.f, 0.f, 0.f, 0.f};
        #pragma unroll
        for (int j = 0; j < 8; j++)
            #pragma unroll
            for (int nt = 0; nt < 2; nt++)
                acc[nt] = __builtin_amdgcn_mfma_f32_16x16x32_bf16(aA[j], BG[nt][j], acc[nt], 0, 0, 0);
        #pragma unroll
        for (int nt = 0; nt < 2; nt++) {
            int col = cb + nt * 16 + m;
            #pragma unroll
            for (int r = 0; r < 4; r++) {
                int row = r0 + g4 * 4 + r;
                float h1v = fmaf(b2f(t1B[(size_t)row * D1 + col]), a1[nt], s1[nt]);
                float v = gelu_exact(acc[nt][r] + bg[nt]) + h1v;
                t2B[(size_t)row * D1 + col] = f2b(v);
                ps[nt] += v; pq[nt] += v * v;
            }
        }
    }
    #pragma unroll
    for (int nt = 0; nt < 2; nt++) {
        float s = ps[nt], q = pq[nt];
        s += __shfl_xor(s, 16); s += __shfl_xor(s, 32);
        q += __shfl_xor(q, 16); q += __shfl_xor(q, 32);
        if (g4 == 0) {
            int col = cb + nt * 16 + m;
            partials[(size_t)blockIdx.x * 512 + col] = s;
            partials[(size_t)blockIdx.x * 512 + 256 + col] = q;
        }
    }
}

// ---------- BN reduce: partials -> per-channel scale/shift ----------

__global__ __launch_bounds__(512) void k_reduce(
    const float* __restrict__ partials, const float* __restrict__ g,
    const float* __restrict__ b, float* __restrict__ sc, float* __restrict__ sh) {
    __shared__ float L[512];
    int j = threadIdx.x;
    float s = 0.f;
    for (int bb = 0; bb < NBLK; bb++) s += partials[(size_t)bb * 512 + j];
    L[j] = s;
    __syncthreads();
    if (j < 256) {
        float m = L[j] * (1.0f / (float)N_NODES);
        float var = L[j + 256] * (1.0f / (float)N_NODES) - m * m;
        float a = g[j] / sqrtf(var + BN_EPS);
        sc[j] = a;
        sh[j] = b[j] - m * a;
    }
}

// ---------- final BN apply: out = sc2*t2 + sh2  (fp32 out) ----------

__global__ __launch_bounds__(256) void k_apply(
    const ushort* __restrict__ t2B, const float* __restrict__ sc,
    const float* __restrict__ sh, float* __restrict__ out) {
    int idx = blockIdx.x * 256 + threadIdx.x;
    size_t base = (size_t)idx * 8;
    int c = (int)(base & 255);
    s16x8 v = *reinterpret_cast<const s16x8*>(&t2B[base]);
    float4 o0, o1;
    o0.x = fmaf(b2f((ushort)v[0]), sc[c + 0], sh[c + 0]);
    o0.y = fmaf(b2f((ushort)v[1]), sc[c + 1], sh[c + 1]);
    o0.z = fmaf(b2f((ushort)v[2]), sc[c + 2], sh[c + 2]);
    o0.w = fmaf(b2f((ushort)v[3]), sc[c + 3], sh[c + 3]);
    o1.x = fmaf(b2f((ushort)v[4]), sc[c + 4], sh[c + 4]);
    o1.y = fmaf(b2f((ushort)v[5]), sc[c + 5], sh[c + 5]);
    o1.z = fmaf(b2f((ushort)v[6]), sc[c + 6], sh[c + 6]);
    o1.w = fmaf(b2f((ushort)v[7]), sc[c + 7], sh[c + 7]);
    *reinterpret_cast<float4*>(&out[base]) = o0;
    *reinterpret_cast<float4*>(&out[base + 4]) = o1;
}

// ---------- launch ----------

static inline size_t align256(size_t x) { return (x + 255) & ~(size_t)255; }

extern "C" void kernel_launch(void* const* d_in, const int* in_sizes, int n_in,
                              void* d_out, int out_size, void* d_ws, size_t ws_size,
                              hipStream_t stream) {
    const float* node_feats = (const float*)d_in[0];
    const float* W_init     = (const float*)d_in[1];
    const float* gcn_w1     = (const float*)d_in[2];
    const float* gcn_b1     = (const float*)d_in[3];
    const float* res_w1     = (const float*)d_in[4];
    const float* res_b1     = (const float*)d_in[5];
    const float* bn_g1      = (const float*)d_in[6];
    const float* bn_b1      = (const float*)d_in[7];
    const float* gcn_w2     = (const float*)d_in[8];
    const float* gcn_b2     = (const float*)d_in[9];
    const float* bn_g2      = (const float*)d_in[10];
    const float* bn_b2      = (const float*)d_in[11];
    const int*   edge_src   = (const int*)d_in[12];
    const int*   edge_dst   = (const int*)d_in[13];
    float* out = (float*)d_out;

    char* p = (char*)d_ws;
    size_t off = 0;
    auto take = [&](size_t bytes) { void* r = p + off; off += align256(bytes); return r; };

    ushort* h0B   = (ushort*)take((size_t)N_NODES * D0 * 2);
    ushort* agg1B = (ushort*)take((size_t)N_NODES * D0 * 2);
    ushort* t1B   = (ushort*)take((size_t)N_NODES * D1 * 2);
    ushort* agg2B = (ushort*)take((size_t)N_NODES * D1 * 2);
    ushort* t2B   = (ushort*)take((size_t)N_NODES * D1 * 2);
    float*  WT    = (float*)take((size_t)F_INF * D0 * 4);
    ushort* WB1   = (ushort*)take((size_t)D1 * D0 * 2);
    ushort* RWB   = (ushort*)take((size_t)D1 * D0 * 2);
    ushort* WB2   = (ushort*)take((size_t)D1 * D1 * 2);
    float*  part1 = (float*)take((size_t)NBLK * 512 * 4);
    float*  part2 = (float*)take((size_t)NBLK * 512 * 4);
    float*  sc1   = (float*)take(256 * 4);
    float*  sh1   = (float*)take(256 * 4);
    float*  sc2   = (float*)take(256 * 4);
    float*  sh2   = (float*)take(256 * 4);
    float*  rsq_out = (float*)take((size_t)N_NODES * 4);
    float*  rsq_in  = (float*)take((size_t)N_NODES * 4);
    int*    degi    = (int*)take((size_t)2 * N_NODES * 4);
    int*    cursor  = (int*)take((size_t)N_NODES * 4);
    int*    row_off = (int*)take((size_t)(N_NODES + 2) * 4);
    int*    csr_src = (int*)take((size_t)E_EDGES * 4);

    hipMemsetAsync(degi, 0, (size_t)2 * N_NODES * 4, stream);
    hipMemsetAsync(cursor, 0, (size_t)N_NODES * 4, stream);

    k_degrees<<<(E_EDGES + 255) / 256, 256, 0, stream>>>(edge_src, edge_dst, degi);
    k_rsq<<<(N_NODES + 255) / 256, 256, 0, stream>>>(degi, rsq_out, rsq_in);
    k_scan<<<1, 1024, 0, stream>>>(degi + N_NODES, row_off);
    k_fill<<<(E_EDGES + 255) / 256, 256, 0, stream>>>(edge_src, edge_dst, row_off, cursor, csr_src);

    k_transpose_winit<<<(F_INF * D0 + 255) / 256, 256, 0, stream>>>(W_init, WT);
    k_prep_l1<<<(D1 * D0) / 256, 256, 0, stream>>>(gcn_w1, res_w1, WB1, RWB);
    k_prep_w2<<<(D1 * D1) / 256, 256, 0, stream>>>(gcn_w2, WB2);

    k_init_gemm<<<N_NODES / 64, 256, 0, stream>>>(node_feats, WT, h0B);

    k_gather1<<<N_NODES / 16, 256, 0, stream>>>(h0B, rsq_out, rsq_in, row_off, csr_src, agg1B);

    k_layer1<<<dim3(NBLK, 2), 256, 0, stream>>>(agg1B, h0B, WB1, RWB, gcn_b1, res_b1, t1B, part1);
    k_reduce<<<1, 512, 0, stream>>>(part1, bn_g1, bn_b1, sc1, sh1);

    k_gather2<<<N_NODES / 8, 256, 0, stream>>>(t1B, sc1, sh1, rsq_out, rsq_in, row_off, csr_src, agg2B);

    k_layer2<<<dim3(NBLK, 2), 256, 0, stream>>>(agg2B, WB2, gcn_b2, t1B, sc1, sh1, t2B, part2);
    k_reduce<<<1, 512, 0, stream>>>(part2, bn_g2, bn_b2, sc2, sh2);

    k_apply<<<(N_NODES * D1 / 8) / 256, 256, 0, stream>>>(t2B, sc2, sh2, out);
}

// Round 5
// 235.668 us; speedup vs baseline: 7.0102x; 1.0495x over previous
//
#include <hip/hip_runtime.h>
#include <hip/hip_bf16.h>
#include <math.h>

#define N_NODES 32768
#define E_EDGES 262144
#define F_INF   74
#define D0      128
#define D1      256
#define BN_EPS  1e-5f
#define RBLK    1024    // row blocks (N_NODES / 32)

typedef float f32x4 __attribute__((ext_vector_type(4)));
typedef short s16x8 __attribute__((ext_vector_type(8)));

__device__ __forceinline__ float b2f(ushort h) { return __uint_as_float(((unsigned)h) << 16); }
__device__ __forceinline__ ushort f2b(float f) {
    unsigned u = __float_as_uint(f);
    return (ushort)((u + 0x7FFFu + ((u >> 16) & 1u)) >> 16);
}
__device__ __forceinline__ float gelu_exact(float x) {
    return 0.5f * x * (1.0f + erff(x * 0.70710678118654752440f));
}

// ---------- graph prep ----------

__global__ void k_degrees(const int* __restrict__ src, const int* __restrict__ dst,
                          int* __restrict__ deg) {
    int e = blockIdx.x * 256 + threadIdx.x;
    if (e < E_EDGES) {
        atomicAdd(&deg[src[e]], 1);
        atomicAdd(&deg[N_NODES + dst[e]], 1);
    }
}

__global__ void k_rsq(const int* __restrict__ deg, float* __restrict__ rsq_out,
                      float* __restrict__ rsq_in) {
    int i = blockIdx.x * 256 + threadIdx.x;
    if (i < N_NODES) {
        int d_o = deg[i];           if (d_o < 1) d_o = 1;
        int d_i = deg[N_NODES + i]; if (d_i < 1) d_i = 1;
        rsq_out[i] = 1.0f / sqrtf((float)d_o);
        rsq_in[i]  = 1.0f / sqrtf((float)d_i);
    }
}

__global__ __launch_bounds__(1024) void k_scan(const int* __restrict__ deg_in,
                                               int* __restrict__ row_off) {
    __shared__ int part[1024];
    int t = threadIdx.x;
    int base = t * 32;
    int loc[32];
    int s = 0;
    #pragma unroll
    for (int i = 0; i < 32; i++) { loc[i] = s; s += deg_in[base + i]; }
    part[t] = s;
    __syncthreads();
    for (int off = 1; off < 1024; off <<= 1) {
        int v = 0;
        if (t >= off) v = part[t - off];
        __syncthreads();
        if (t >= off) part[t] += v;
        __syncthreads();
    }
    int pre = (t == 0) ? 0 : part[t - 1];
    #pragma unroll
    for (int i = 0; i < 32; i++) row_off[base + i] = pre + loc[i];
    if (t == 1023) row_off[N_NODES] = part[1023];
}

__global__ void k_fill(const int* __restrict__ src, const int* __restrict__ dst,
                       const int* __restrict__ row_off, int* __restrict__ cursor,
                       int* __restrict__ csr_src) {
    int e = blockIdx.x * 256 + threadIdx.x;
    if (e < E_EDGES) {
        int d = dst[e];
        int slot = atomicAdd(&cursor[d], 1);
        csr_src[row_off[d] + slot] = src[e];
    }
}

// ---------- weight prep ----------

__global__ void k_transpose_winit(const float* __restrict__ W, float* __restrict__ WT) {
    int idx = blockIdx.x * 256 + threadIdx.x;
    if (idx < F_INF * D0) {
        int f = idx / D0, c = idx % D0;
        WT[f * D0 + c] = W[c * F_INF + f];
    }
}

// WB1[n][k] = bf16(gcn_w1[k][n]); RWB[n][k] = bf16(res_w1[n][k])
__global__ void k_prep_l1(const float* __restrict__ w1, const float* __restrict__ rw,
                          ushort* __restrict__ WB1, ushort* __restrict__ RWB) {
    int idx = blockIdx.x * 256 + threadIdx.x;   // 256*128
    int n = idx >> 7, k = idx & 127;
    WB1[idx] = f2b(w1[k * D1 + n]);
    RWB[idx] = f2b(rw[idx]);
}

// WB2[n][k] = bf16(gcn_w2[k][n])
__global__ void k_prep_w2(const float* __restrict__ w2, ushort* __restrict__ WB2) {
    int idx = blockIdx.x * 256 + threadIdx.x;   // 256*256
    int n = idx >> 8, k = idx & 255;
    WB2[idx] = f2b(w2[k * D1 + n]);
}

// ---------- init GEMM: h0 = nf @ W_init^T  -> bf16 ----------

__global__ __launch_bounds__(256) void k_init_gemm(
    const float* __restrict__ nf, const float* __restrict__ WT,
    ushort* __restrict__ h0) {
    __shared__ float sNF[64 * 76];
    int nb = blockIdx.x * 64;
    int tid = threadIdx.x;
    for (int idx = tid; idx < 64 * F_INF; idx += 256) {
        int row = idx / F_INF, f = idx % F_INF;
        sNF[row * 76 + f] = nf[(size_t)nb * F_INF + idx];
    }
    __syncthreads();
    int tc = tid & 31;
    int tn = tid >> 5;
    int c0 = tc * 4;
    float acc[8][4];
    #pragma unroll
    for (int i = 0; i < 8; i++)
        #pragma unroll
        for (int j = 0; j < 4; j++) acc[i][j] = 0.f;
    for (int k = 0; k < F_INF; k++) {
        float4 w = *reinterpret_cast<const float4*>(&WT[k * D0 + c0]);
        #pragma unroll
        for (int i = 0; i < 8; i++) {
            float a = sNF[(tn * 8 + i) * 76 + k];
            acc[i][0] += a * w.x; acc[i][1] += a * w.y;
            acc[i][2] += a * w.z; acc[i][3] += a * w.w;
        }
    }
    #pragma unroll
    for (int i = 0; i < 8; i++) {
        ushort4 o;
        o.x = f2b(acc[i][0]); o.y = f2b(acc[i][1]);
        o.z = f2b(acc[i][2]); o.w = f2b(acc[i][3]);
        *reinterpret_cast<ushort4*>(&h0[(size_t)(nb + tn * 8 + i) * D0 + c0]) = o;
    }
}

// ---------- gather1: agg1 = rsq_in * sum rsq_out[s]*h0[s]  (4-wide pipelined) ----------

__global__ __launch_bounds__(256) void k_gather1(
    const ushort* __restrict__ x, const float* __restrict__ rsq_out,
    const float* __restrict__ rsq_in,
    const int* __restrict__ row_off, const int* __restrict__ csr_src,
    ushort* __restrict__ agg) {
    int tid = threadIdx.x;
    int node = blockIdx.x * 16 + (tid >> 4);
    int f = (tid & 15) * 8;
    int beg = row_off[node], end = row_off[node + 1];
    float a[8];
    #pragma unroll
    for (int j = 0; j < 8; j++) a[j] = 0.f;
    int e = beg;
    for (; e + 3 < end; e += 4) {
        int s0 = csr_src[e], s1 = csr_src[e + 1], s2 = csr_src[e + 2], s3 = csr_src[e + 3];
        float c0 = rsq_out[s0], c1 = rsq_out[s1], c2 = rsq_out[s2], c3 = rsq_out[s3];
        s16x8 v0 = *reinterpret_cast<const s16x8*>(&x[(size_t)s0 * D0 + f]);
        s16x8 v1 = *reinterpret_cast<const s16x8*>(&x[(size_t)s1 * D0 + f]);
        s16x8 v2 = *reinterpret_cast<const s16x8*>(&x[(size_t)s2 * D0 + f]);
        s16x8 v3 = *reinterpret_cast<const s16x8*>(&x[(size_t)s3 * D0 + f]);
        #pragma unroll
        for (int j = 0; j < 8; j++)
            a[j] += b2f((ushort)v0[j]) * c0 + b2f((ushort)v1[j]) * c1 +
                    b2f((ushort)v2[j]) * c2 + b2f((ushort)v3[j]) * c3;
    }
    for (; e < end; e++) {
        int s = csr_src[e];
        float sc = rsq_out[s];
        s16x8 v = *reinterpret_cast<const s16x8*>(&x[(size_t)s * D0 + f]);
        #pragma unroll
        for (int j = 0; j < 8; j++) a[j] += b2f((ushort)v[j]) * sc;
    }
    float si = rsq_in[node];
    s16x8 o;
    #pragma unroll
    for (int j = 0; j < 8; j++) o[j] = (short)f2b(a[j] * si);
    *reinterpret_cast<s16x8*>(&agg[(size_t)node * D0 + f]) = o;
}

// ---------- gather2: agg2 = rsq_in * (sc1 * sum sc_s*t1[s] + sh1 * sum sc_s) ----------

__global__ __launch_bounds__(256) void k_gather2(
    const ushort* __restrict__ t1, const float* __restrict__ sc1,
    const float* __restrict__ sh1,
    const float* __restrict__ rsq_out, const float* __restrict__ rsq_in,
    const int* __restrict__ row_off, const int* __restrict__ csr_src,
    ushort* __restrict__ agg) {
    int tid = threadIdx.x;
    int node = blockIdx.x * 8 + (tid >> 5);
    int f = (tid & 31) * 8;
    int beg = row_off[node], end = row_off[node + 1];
    float a[8];
    #pragma unroll
    for (int j = 0; j < 8; j++) a[j] = 0.f;
    float ssum = 0.f;
    int e = beg;
    for (; e + 3 < end; e += 4) {
        int s0 = csr_src[e], s1 = csr_src[e + 1], s2 = csr_src[e + 2], s3 = csr_src[e + 3];
        float c0 = rsq_out[s0], c1 = rsq_out[s1], c2 = rsq_out[s2], c3 = rsq_out[s3];
        s16x8 v0 = *reinterpret_cast<const s16x8*>(&t1[(size_t)s0 * D1 + f]);
        s16x8 v1 = *reinterpret_cast<const s16x8*>(&t1[(size_t)s1 * D1 + f]);
        s16x8 v2 = *reinterpret_cast<const s16x8*>(&t1[(size_t)s2 * D1 + f]);
        s16x8 v3 = *reinterpret_cast<const s16x8*>(&t1[(size_t)s3 * D1 + f]);
        ssum += c0 + c1 + c2 + c3;
        #pragma unroll
        for (int j = 0; j < 8; j++)
            a[j] += b2f((ushort)v0[j]) * c0 + b2f((ushort)v1[j]) * c1 +
                    b2f((ushort)v2[j]) * c2 + b2f((ushort)v3[j]) * c3;
    }
    for (; e < end; e++) {
        int s = csr_src[e];
        float sc = rsq_out[s];
        s16x8 v = *reinterpret_cast<const s16x8*>(&t1[(size_t)s * D1 + f]);
        ssum += sc;
        #pragma unroll
        for (int j = 0; j < 8; j++) a[j] += b2f((ushort)v[j]) * sc;
    }
    float si = rsq_in[node];
    s16x8 o;
    #pragma unroll
    for (int j = 0; j < 8; j++) {
        float val = (sc1[f + j] * a[j] + sh1[f + j] * ssum) * si;
        o[j] = (short)f2b(val);
    }
    *reinterpret_cast<s16x8*>(&agg[(size_t)node * D1 + f]) = o;
}

// ---------- layer1 MFMA: grid (RBLK, 4); block = 32 rows x 64 cols; wave = 16 cols ----------
// partials layout: part[(stat*256 + col) * RBLK + blockIdx.x]

__global__ __launch_bounds__(256) void k_layer1(
    const ushort* __restrict__ aggB, const ushort* __restrict__ h0B,
    const ushort* __restrict__ WB1, const ushort* __restrict__ RWB,
    const float* __restrict__ b1, const float* __restrict__ rb,
    ushort* __restrict__ t1B, float* __restrict__ partials) {
    int tid = threadIdx.x;
    int w = tid >> 6, lane = tid & 63, m = lane & 15, g4 = lane >> 4;
    int col = blockIdx.y * 64 + w * 16 + m;
    s16x8 BG[4], BR[4];
    #pragma unroll
    for (int j = 0; j < 4; j++) {
        BG[j] = *reinterpret_cast<const s16x8*>(&WB1[(size_t)col * D0 + j * 32 + g4 * 8]);
        BR[j] = *reinterpret_cast<const s16x8*>(&RWB[(size_t)col * D0 + j * 32 + g4 * 8]);
    }
    float bg = b1[col], brv = rb[col];
    int rbase = blockIdx.x * 32;
    float ps = 0.f, pq = 0.f;
    #pragma unroll
    for (int rt = 0; rt < 2; rt++) {
        int r0 = rbase + rt * 16;
        s16x8 aA[4], aH[4];
        #pragma unroll
        for (int j = 0; j < 4; j++) {
            aA[j] = *reinterpret_cast<const s16x8*>(&aggB[(size_t)(r0 + m) * D0 + j * 32 + g4 * 8]);
            aH[j] = *reinterpret_cast<const s16x8*>(&h0B[(size_t)(r0 + m) * D0 + j * 32 + g4 * 8]);
        }
        f32x4 accG = (f32x4){0.f, 0.f, 0.f, 0.f};
        f32x4 accR = (f32x4){0.f, 0.f, 0.f, 0.f};
        #pragma unroll
        for (int j = 0; j < 4; j++) {
            accG = __builtin_amdgcn_mfma_f32_16x16x32_bf16(aA[j], BG[j], accG, 0, 0, 0);
            accR = __builtin_amdgcn_mfma_f32_16x16x32_bf16(aH[j], BR[j], accR, 0, 0, 0);
        }
        #pragma unroll
        for (int r = 0; r < 4; r++) {
            int row = r0 + g4 * 4 + r;
            float v = gelu_exact(accG[r] + bg) + accR[r] + brv;
            t1B[(size_t)row * D1 + col] = f2b(v);
            ps += v; pq += v * v;
        }
    }
    ps += __shfl_xor(ps, 16); ps += __shfl_xor(ps, 32);
    pq += __shfl_xor(pq, 16); pq += __shfl_xor(pq, 32);
    if (g4 == 0) {
        partials[(size_t)col * RBLK + blockIdx.x] = ps;
        partials[(size_t)(256 + col) * RBLK + blockIdx.x] = pq;
    }
}

// ---------- layer2 MFMA: t2 = gelu(agg2@w2+b2) + (sc1*t1+sh1) ----------

__global__ __launch_bounds__(256) void k_layer2(
    const ushort* __restrict__ aggB, const ushort* __restrict__ WB2,
    const float* __restrict__ b2,
    const ushort* __restrict__ t1B, const float* __restrict__ sc1,
    const float* __restrict__ sh1,
    ushort* __restrict__ t2B, float* __restrict__ partials) {
    int tid = threadIdx.x;
    int w = tid >> 6, lane = tid & 63, m = lane & 15, g4 = lane >> 4;
    int col = blockIdx.y * 64 + w * 16 + m;
    s16x8 BG[8];
    #pragma unroll
    for (int j = 0; j < 8; j++)
        BG[j] = *reinterpret_cast<const s16x8*>(&WB2[(size_t)col * D1 + j * 32 + g4 * 8]);
    float bg = b2[col], a1 = sc1[col], s1 = sh1[col];
    int rbase = blockIdx.x * 32;
    float ps = 0.f, pq = 0.f;
    #pragma unroll
    for (int rt = 0; rt < 2; rt++) {
        int r0 = rbase + rt * 16;
        s16x8 aA[8];
        #pragma unroll
        for (int j = 0; j < 8; j++)
            aA[j] = *reinterpret_cast<const s16x8*>(&aggB[(size_t)(r0 + m) * D1 + j * 32 + g4 * 8]);
        f32x4 acc = (f32x4){0.f, 0.f, 0.f, 0.f};
        #pragma unroll
        for (int j = 0; j < 8; j++)
            acc = __builtin_amdgcn_mfma_f32_16x16x32_bf16(aA[j], BG[j], acc, 0, 0, 0);
        #pragma unroll
        for (int r = 0; r < 4; r++) {
            int row = r0 + g4 * 4 + r;
            float h1v = fmaf(b2f(t1B[(size_t)row * D1 + col]), a1, s1);
            float v = gelu_exact(acc[r] + bg) + h1v;
            t2B[(size_t)row * D1 + col] = f2b(v);
            ps += v; pq += v * v;
        }
    }
    ps += __shfl_xor(ps, 16); ps += __shfl_xor(ps, 32);
    pq += __shfl_xor(pq, 16); pq += __shfl_xor(pq, 32);
    if (g4 == 0) {
        partials[(size_t)col * RBLK + blockIdx.x] = ps;
        partials[(size_t)(256 + col) * RBLK + blockIdx.x] = pq;
    }
}

// ---------- BN reduce: one block per channel ----------

__global__ __launch_bounds__(256) void k_reduce(
    const float* __restrict__ partials, const float* __restrict__ g,
    const float* __restrict__ b, float* __restrict__ sc, float* __restrict__ sh) {
    int c = blockIdx.x;
    int t = threadIdx.x;
    const float* ps = partials + (size_t)c * RBLK;
    const float* pq = partials + (size_t)(256 + c) * RBLK;
    float s = ps[t] + ps[t + 256] + ps[t + 512] + ps[t + 768];
    float q = pq[t] + pq[t + 256] + pq[t + 512] + pq[t + 768];
    __shared__ float Ls[256], Lq[256];
    Ls[t] = s; Lq[t] = q;
    __syncthreads();
    for (int o = 128; o > 0; o >>= 1) {
        if (t < o) { Ls[t] += Ls[t + o]; Lq[t] += Lq[t + o]; }
        __syncthreads();
    }
    if (t == 0) {
        float m = Ls[0] * (1.0f / (float)N_NODES);
        float var = Lq[0] * (1.0f / (float)N_NODES) - m * m;
        float a = g[c] / sqrtf(var + BN_EPS);
        sc[c] = a;
        sh[c] = b[c] - m * a;
    }
}

// ---------- final BN apply: out = sc2*t2 + sh2  (fp32 out) ----------

__global__ __launch_bounds__(256) void k_apply(
    const ushort* __restrict__ t2B, const float* __restrict__ sc,
    const float* __restrict__ sh, float* __restrict__ out) {
    int idx = blockIdx.x * 256 + threadIdx.x;
    size_t base = (size_t)idx * 8;
    int c = (int)(base & 255);
    s16x8 v = *reinterpret_cast<const s16x8*>(&t2B[base]);
    float4 o0, o1;
    o0.x = fmaf(b2f((ushort)v[0]), sc[c + 0], sh[c + 0]);
    o0.y = fmaf(b2f((ushort)v[1]), sc[c + 1], sh[c + 1]);
    o0.z = fmaf(b2f((ushort)v[2]), sc[c + 2], sh[c + 2]);
    o0.w = fmaf(b2f((ushort)v[3]), sc[c + 3], sh[c + 3]);
    o1.x = fmaf(b2f((ushort)v[4]), sc[c + 4], sh[c + 4]);
    o1.y = fmaf(b2f((ushort)v[5]), sc[c + 5], sh[c + 5]);
    o1.z = fmaf(b2f((ushort)v[6]), sc[c + 6], sh[c + 6]);
    o1.w = fmaf(b2f((ushort)v[7]), sc[c + 7], sh[c + 7]);
    *reinterpret_cast<float4*>(&out[base]) = o0;
    *reinterpret_cast<float4*>(&out[base + 4]) = o1;
}

// ---------- launch ----------

static inline size_t align256(size_t x) { return (x + 255) & ~(size_t)255; }

extern "C" void kernel_launch(void* const* d_in, const int* in_sizes, int n_in,
                              void* d_out, int out_size, void* d_ws, size_t ws_size,
                              hipStream_t stream) {
    const float* node_feats = (const float*)d_in[0];
    const float* W_init     = (const float*)d_in[1];
    const float* gcn_w1     = (const float*)d_in[2];
    const float* gcn_b1     = (const float*)d_in[3];
    const float* res_w1     = (const float*)d_in[4];
    const float* res_b1     = (const float*)d_in[5];
    const float* bn_g1      = (const float*)d_in[6];
    const float* bn_b1      = (const float*)d_in[7];
    const float* gcn_w2     = (const float*)d_in[8];
    const float* gcn_b2     = (const float*)d_in[9];
    const float* bn_g2      = (const float*)d_in[10];
    const float* bn_b2      = (const float*)d_in[11];
    const int*   edge_src   = (const int*)d_in[12];
    const int*   edge_dst   = (const int*)d_in[13];
    float* out = (float*)d_out;

    char* p = (char*)d_ws;
    size_t off = 0;
    auto take = [&](size_t bytes) { void* r = p + off; off += align256(bytes); return r; };

    ushort* h0B   = (ushort*)take((size_t)N_NODES * D0 * 2);
    ushort* agg1B = (ushort*)take((size_t)N_NODES * D0 * 2);
    ushort* t1B   = (ushort*)take((size_t)N_NODES * D1 * 2);
    ushort* agg2B = (ushort*)take((size_t)N_NODES * D1 * 2);
    ushort* t2B   = (ushort*)take((size_t)N_NODES * D1 * 2);
    float*  WT    = (float*)take((size_t)F_INF * D0 * 4);
    ushort* WB1   = (ushort*)take((size_t)D1 * D0 * 2);
    ushort* RWB   = (ushort*)take((size_t)D1 * D0 * 2);
    ushort* WB2   = (ushort*)take((size_t)D1 * D1 * 2);
    float*  part1 = (float*)take((size_t)2 * 256 * RBLK * 4);
    float*  part2 = (float*)take((size_t)2 * 256 * RBLK * 4);
    float*  sc1   = (float*)take(256 * 4);
    float*  sh1   = (float*)take(256 * 4);
    float*  sc2   = (float*)take(256 * 4);
    float*  sh2   = (float*)take(256 * 4);
    float*  rsq_out = (float*)take((size_t)N_NODES * 4);
    float*  rsq_in  = (float*)take((size_t)N_NODES * 4);
    int*    degi    = (int*)take((size_t)2 * N_NODES * 4);
    int*    cursor  = (int*)take((size_t)N_NODES * 4);
    int*    row_off = (int*)take((size_t)(N_NODES + 2) * 4);
    int*    csr_src = (int*)take((size_t)E_EDGES * 4);

    hipMemsetAsync(degi, 0, (size_t)2 * N_NODES * 4, stream);
    hipMemsetAsync(cursor, 0, (size_t)N_NODES * 4, stream);

    k_degrees<<<(E_EDGES + 255) / 256, 256, 0, stream>>>(edge_src, edge_dst, degi);
    k_rsq<<<(N_NODES + 255) / 256, 256, 0, stream>>>(degi, rsq_out, rsq_in);
    k_scan<<<1, 1024, 0, stream>>>(degi + N_NODES, row_off);
    k_fill<<<(E_EDGES + 255) / 256, 256, 0, stream>>>(edge_src, edge_dst, row_off, cursor, csr_src);

    k_transpose_winit<<<(F_INF * D0 + 255) / 256, 256, 0, stream>>>(W_init, WT);
    k_prep_l1<<<(D1 * D0) / 256, 256, 0, stream>>>(gcn_w1, res_w1, WB1, RWB);
    k_prep_w2<<<(D1 * D1) / 256, 256, 0, stream>>>(gcn_w2, WB2);

    k_init_gemm<<<N_NODES / 64, 256, 0, stream>>>(node_feats, WT, h0B);

    k_gather1<<<N_NODES / 16, 256, 0, stream>>>(h0B, rsq_out, rsq_in, row_off, csr_src, agg1B);

    k_layer1<<<dim3(RBLK, 4), 256, 0, stream>>>(agg1B, h0B, WB1, RWB, gcn_b1, res_b1, t1B, part1);
    k_reduce<<<256, 256, 0, stream>>>(part1, bn_g1, bn_b1, sc1, sh1);

    k_gather2<<<N_NODES / 8, 256, 0, stream>>>(t1B, sc1, sh1, rsq_out, rsq_in, row_off, csr_src, agg2B);

    k_layer2<<<dim3(RBLK, 4), 256, 0, stream>>>(agg2B, WB2, gcn_b2, t1B, sc1, sh1, t2B, part2);
    k_reduce<<<256, 256, 0, stream>>>(part2, bn_g2, bn_b2, sc2, sh2);

    k_apply<<<(N_NODES * D1 / 8) / 256, 256, 0, stream>>>(t2B, sc2, sh2, out);
}

// Round 6
// 218.536 us; speedup vs baseline: 7.5598x; 1.0784x over previous
//
#include <hip/hip_runtime.h>
#include <hip/hip_bf16.h>
#include <math.h>

#define N_NODES 32768
#define E_EDGES 262144
#define F_INF   74
#define D0      128
#define D1      256
#define BN_EPS  1e-5f
#define RBLK    1024    // row blocks (N_NODES / 32)

typedef float f32x4 __attribute__((ext_vector_type(4)));
typedef short s16x8 __attribute__((ext_vector_type(8)));

__device__ __forceinline__ float b2f(ushort h) { return __uint_as_float(((unsigned)h) << 16); }
__device__ __forceinline__ ushort f2b(float f) {
    unsigned u = __float_as_uint(f);
    return (ushort)((u + 0x7FFFu + ((u >> 16) & 1u)) >> 16);
}
__device__ __forceinline__ float gelu_exact(float x) {
    return 0.5f * x * (1.0f + erff(x * 0.70710678118654752440f));
}

// ---------- graph prep ----------

__global__ void k_degrees(const int* __restrict__ src, const int* __restrict__ dst,
                          int* __restrict__ deg) {
    int e = blockIdx.x * 256 + threadIdx.x;
    if (e < E_EDGES) {
        atomicAdd(&deg[src[e]], 1);
        atomicAdd(&deg[N_NODES + dst[e]], 1);
    }
}

// scan in-degrees -> row_off; also rsq factors; also zero cursor
__global__ __launch_bounds__(1024) void k_scan(const int* __restrict__ deg,
                                               int* __restrict__ row_off,
                                               float* __restrict__ rsq_out,
                                               float* __restrict__ rsq_in,
                                               int* __restrict__ cursor) {
    __shared__ int part[1024];
    int t = threadIdx.x;
    int base = t * 32;
    int loc[32];
    int s = 0;
    #pragma unroll
    for (int i = 0; i < 32; i++) { loc[i] = s; s += deg[N_NODES + base + i]; }
    part[t] = s;
    #pragma unroll
    for (int i = 0; i < 32; i++) {
        int n = base + i;
        int d_o = deg[n];           if (d_o < 1) d_o = 1;
        int d_i = deg[N_NODES + n]; if (d_i < 1) d_i = 1;
        rsq_out[n] = 1.0f / sqrtf((float)d_o);
        rsq_in[n]  = 1.0f / sqrtf((float)d_i);
        cursor[n] = 0;
    }
    __syncthreads();
    for (int off = 1; off < 1024; off <<= 1) {
        int v = 0;
        if (t >= off) v = part[t - off];
        __syncthreads();
        if (t >= off) part[t] += v;
        __syncthreads();
    }
    int pre = (t == 0) ? 0 : part[t - 1];
    #pragma unroll
    for (int i = 0; i < 32; i++) row_off[base + i] = pre + loc[i];
    if (t == 1023) row_off[N_NODES] = part[1023];
}

__global__ void k_fill(const int* __restrict__ src, const int* __restrict__ dst,
                       const int* __restrict__ row_off, int* __restrict__ cursor,
                       int* __restrict__ csr_src) {
    int e = blockIdx.x * 256 + threadIdx.x;
    if (e < E_EDGES) {
        int d = dst[e];
        int slot = atomicAdd(&cursor[d], 1);
        csr_src[row_off[d] + slot] = src[e];
    }
}

// ---------- merged weight prep ----------
// WT[f][c] = W_init[c][f] (fp32);  WB1[n][k]=bf16(gcn_w1[k][n]); RWB[n][k]=bf16(res_w1[n][k]);
// WB2[n][k]=bf16(gcn_w2[k][n])
__global__ void k_prep(const float* __restrict__ Wi, const float* __restrict__ w1,
                       const float* __restrict__ rw, const float* __restrict__ w2,
                       float* __restrict__ WT, ushort* __restrict__ WB1,
                       ushort* __restrict__ RWB, ushort* __restrict__ WB2) {
    int idx = blockIdx.x * 256 + threadIdx.x;   // 65536 threads
    {   // WB2
        int n = idx >> 8, k = idx & 255;
        WB2[idx] = f2b(w2[k * D1 + n]);
    }
    if (idx < D1 * D0) {
        int n = idx >> 7, k = idx & 127;
        WB1[idx] = f2b(w1[k * D1 + n]);
        RWB[idx] = f2b(rw[idx]);
    }
    if (idx < F_INF * D0) {
        int f = idx / D0, c = idx % D0;
        WT[f * D0 + c] = Wi[c * F_INF + f];
    }
}

// ---------- init GEMM: h0 = nf @ W_init^T  -> bf16 ----------

__global__ __launch_bounds__(256) void k_init_gemm(
    const float* __restrict__ nf, const float* __restrict__ WT,
    ushort* __restrict__ h0) {
    __shared__ float sNF[64 * 76];
    int nb = blockIdx.x * 64;
    int tid = threadIdx.x;
    for (int idx = tid; idx < 64 * F_INF; idx += 256) {
        int row = idx / F_INF, f = idx % F_INF;
        sNF[row * 76 + f] = nf[(size_t)nb * F_INF + idx];
    }
    __syncthreads();
    int tc = tid & 31;
    int tn = tid >> 5;
    int c0 = tc * 4;
    float acc[8][4];
    #pragma unroll
    for (int i = 0; i < 8; i++)
        #pragma unroll
        for (int j = 0; j < 4; j++) acc[i][j] = 0.f;
    for (int k = 0; k < F_INF; k++) {
        float4 w = *reinterpret_cast<const float4*>(&WT[k * D0 + c0]);
        #pragma unroll
        for (int i = 0; i < 8; i++) {
            float a = sNF[(tn * 8 + i) * 76 + k];
            acc[i][0] += a * w.x; acc[i][1] += a * w.y;
            acc[i][2] += a * w.z; acc[i][3] += a * w.w;
        }
    }
    #pragma unroll
    for (int i = 0; i < 8; i++) {
        ushort4 o;
        o.x = f2b(acc[i][0]); o.y = f2b(acc[i][1]);
        o.z = f2b(acc[i][2]); o.w = f2b(acc[i][3]);
        *reinterpret_cast<ushort4*>(&h0[(size_t)(nb + tn * 8 + i) * D0 + c0]) = o;
    }
}

// ---------- layer1 fused: gather(h0) -> LDS, then MFMA + gelu + residual + BN partials ----------
// grid (RBLK); 512 threads = 8 waves; block = 32 rows x 256 cols; wave owns 32 cols.
// LDS tile swizzle: 16B slot index XOR (row & 15).

__global__ __launch_bounds__(512) void k_layer1f(
    const ushort* __restrict__ h0B,
    const float* __restrict__ rsq_out, const float* __restrict__ rsq_in,
    const int* __restrict__ row_off, const int* __restrict__ csr_src,
    const ushort* __restrict__ WB1, const ushort* __restrict__ RWB,
    const float* __restrict__ b1, const float* __restrict__ rb,
    ushort* __restrict__ t1B, float* __restrict__ partials) {
    __shared__ ushort sA[32 * 128];
    int tid = threadIdx.x;
    int rbase = blockIdx.x * 32;
    // ---- gather phase: 16 threads per node, 8 cols each ----
    {
        int nloc = tid >> 4;
        int node = rbase + nloc;
        int f = (tid & 15) * 8;
        int beg = row_off[node], end = row_off[node + 1];
        float a[8];
        #pragma unroll
        for (int j = 0; j < 8; j++) a[j] = 0.f;
        int e = beg;
        for (; e + 3 < end; e += 4) {
            int s0 = csr_src[e], s1 = csr_src[e + 1], s2 = csr_src[e + 2], s3 = csr_src[e + 3];
            float c0 = rsq_out[s0], c1 = rsq_out[s1], c2 = rsq_out[s2], c3 = rsq_out[s3];
            s16x8 v0 = *reinterpret_cast<const s16x8*>(&h0B[(size_t)s0 * D0 + f]);
            s16x8 v1 = *reinterpret_cast<const s16x8*>(&h0B[(size_t)s1 * D0 + f]);
            s16x8 v2 = *reinterpret_cast<const s16x8*>(&h0B[(size_t)s2 * D0 + f]);
            s16x8 v3 = *reinterpret_cast<const s16x8*>(&h0B[(size_t)s3 * D0 + f]);
            #pragma unroll
            for (int j = 0; j < 8; j++)
                a[j] += b2f((ushort)v0[j]) * c0 + b2f((ushort)v1[j]) * c1 +
                        b2f((ushort)v2[j]) * c2 + b2f((ushort)v3[j]) * c3;
        }
        for (; e < end; e++) {
            int s = csr_src[e];
            float sc = rsq_out[s];
            s16x8 v = *reinterpret_cast<const s16x8*>(&h0B[(size_t)s * D0 + f]);
            #pragma unroll
            for (int j = 0; j < 8; j++) a[j] += b2f((ushort)v[j]) * sc;
        }
        float si = rsq_in[node];
        s16x8 o;
        #pragma unroll
        for (int j = 0; j < 8; j++) o[j] = (short)f2b(a[j] * si);
        int boff = nloc * 256 + ((f * 2) ^ ((nloc & 15) << 4));
        *reinterpret_cast<s16x8*>(((char*)sA) + boff) = o;
    }
    __syncthreads();
    // ---- MFMA phase ----
    int w = tid >> 6, lane = tid & 63, m = lane & 15, g4 = lane >> 4;
    int cb = w * 32;
    s16x8 BG[2][4], BR[2][4];
    #pragma unroll
    for (int nt = 0; nt < 2; nt++)
        #pragma unroll
        for (int j = 0; j < 4; j++) {
            BG[nt][j] = *reinterpret_cast<const s16x8*>(&WB1[(size_t)(cb + nt * 16 + m) * D0 + j * 32 + g4 * 8]);
            BR[nt][j] = *reinterpret_cast<const s16x8*>(&RWB[(size_t)(cb + nt * 16 + m) * D0 + j * 32 + g4 * 8]);
        }
    float bg[2], brv[2];
    #pragma unroll
    for (int nt = 0; nt < 2; nt++) {
        bg[nt]  = b1[cb + nt * 16 + m];
        brv[nt] = rb[cb + nt * 16 + m];
    }
    float ps[2] = {0.f, 0.f}, pq[2] = {0.f, 0.f};
    #pragma unroll
    for (int rt = 0; rt < 2; rt++) {
        int row = rt * 16 + m;
        s16x8 aA[4], aH[4];
        #pragma unroll
        for (int j = 0; j < 4; j++) {
            int boff = row * 256 + (((j * 4 + g4) * 16) ^ ((row & 15) << 4));
            aA[j] = *reinterpret_cast<const s16x8*>(((const char*)sA) + boff);
            aH[j] = *reinterpret_cast<const s16x8*>(&h0B[(size_t)(rbase + row) * D0 + j * 32 + g4 * 8]);
        }
        f32x4 accG[2], accR[2];
        #pragma unroll
        for (int nt = 0; nt < 2; nt++) {
            accG[nt] = (f32x4){0.f, 0.f, 0.f, 0.f};
            accR[nt] = (f32x4){0.f, 0.f, 0.f, 0.f};
        }
        #pragma unroll
        for (int j = 0; j < 4; j++)
            #pragma unroll
            for (int nt = 0; nt < 2; nt++) {
                accG[nt] = __builtin_amdgcn_mfma_f32_16x16x32_bf16(aA[j], BG[nt][j], accG[nt], 0, 0, 0);
                accR[nt] = __builtin_amdgcn_mfma_f32_16x16x32_bf16(aH[j], BR[nt][j], accR[nt], 0, 0, 0);
            }
        #pragma unroll
        for (int nt = 0; nt < 2; nt++) {
            int col = cb + nt * 16 + m;
            #pragma unroll
            for (int r = 0; r < 4; r++) {
                int orow = rbase + rt * 16 + g4 * 4 + r;
                float v = gelu_exact(accG[nt][r] + bg[nt]) + accR[nt][r] + brv[nt];
                t1B[(size_t)orow * D1 + col] = f2b(v);
                ps[nt] += v; pq[nt] += v * v;
            }
        }
    }
    #pragma unroll
    for (int nt = 0; nt < 2; nt++) {
        float s = ps[nt], q = pq[nt];
        s += __shfl_xor(s, 16); s += __shfl_xor(s, 32);
        q += __shfl_xor(q, 16); q += __shfl_xor(q, 32);
        if (g4 == 0) {
            int col = cb + nt * 16 + m;
            partials[(size_t)col * RBLK + blockIdx.x] = s;
            partials[(size_t)(256 + col) * RBLK + blockIdx.x] = q;
        }
    }
}

// ---------- layer2 fused: gather(BN1(t1)) -> LDS, then MFMA + gelu + residual + BN partials ----------

__global__ __launch_bounds__(512) void k_layer2f(
    const ushort* __restrict__ t1B,
    const float* __restrict__ sc1, const float* __restrict__ sh1,
    const float* __restrict__ rsq_out, const float* __restrict__ rsq_in,
    const int* __restrict__ row_off, const int* __restrict__ csr_src,
    const ushort* __restrict__ WB2, const float* __restrict__ b2,
    ushort* __restrict__ t2B, float* __restrict__ partials) {
    __shared__ ushort sA[32 * 256];
    int tid = threadIdx.x;
    int rbase = blockIdx.x * 32;
    // ---- gather phase: 16 threads per node, 2 chunks of 8 cols each ----
    {
        int nloc = tid >> 4;
        int node = rbase + nloc;
        int f0 = (tid & 15) * 8;          // and f0+128
        int beg = row_off[node], end = row_off[node + 1];
        float a0[8], a1[8];
        #pragma unroll
        for (int j = 0; j < 8; j++) { a0[j] = 0.f; a1[j] = 0.f; }
        float ssum = 0.f;
        int e = beg;
        for (; e + 1 < end; e += 2) {
            int s0 = csr_src[e], s1 = csr_src[e + 1];
            float c0 = rsq_out[s0], c1 = rsq_out[s1];
            s16x8 v00 = *reinterpret_cast<const s16x8*>(&t1B[(size_t)s0 * D1 + f0]);
            s16x8 v01 = *reinterpret_cast<const s16x8*>(&t1B[(size_t)s0 * D1 + f0 + 128]);
            s16x8 v10 = *reinterpret_cast<const s16x8*>(&t1B[(size_t)s1 * D1 + f0]);
            s16x8 v11 = *reinterpret_cast<const s16x8*>(&t1B[(size_t)s1 * D1 + f0 + 128]);
            ssum += c0 + c1;
            #pragma unroll
            for (int j = 0; j < 8; j++) {
                a0[j] += b2f((ushort)v00[j]) * c0 + b2f((ushort)v10[j]) * c1;
                a1[j] += b2f((ushort)v01[j]) * c0 + b2f((ushort)v11[j]) * c1;
            }
        }
        for (; e < end; e++) {
            int s = csr_src[e];
            float sc = rsq_out[s];
            s16x8 v0 = *reinterpret_cast<const s16x8*>(&t1B[(size_t)s * D1 + f0]);
            s16x8 v1 = *reinterpret_cast<const s16x8*>(&t1B[(size_t)s * D1 + f0 + 128]);
            ssum += sc;
            #pragma unroll
            for (int j = 0; j < 8; j++) {
                a0[j] += b2f((ushort)v0[j]) * sc;
                a1[j] += b2f((ushort)v1[j]) * sc;
            }
        }
        float si = rsq_in[node];
        s16x8 o0, o1;
        #pragma unroll
        for (int j = 0; j < 8; j++) {
            o0[j] = (short)f2b((sc1[f0 + j] * a0[j] + sh1[f0 + j] * ssum) * si);
            o1[j] = (short)f2b((sc1[f0 + 128 + j] * a1[j] + sh1[f0 + 128 + j] * ssum) * si);
        }
        int swz = (nloc & 15) << 4;
        int b0 = nloc * 512 + ((f0 * 2) ^ swz);
        int b1_ = nloc * 512 + (((f0 + 128) * 2) ^ swz);
        *reinterpret_cast<s16x8*>(((char*)sA) + b0) = o0;
        *reinterpret_cast<s16x8*>(((char*)sA) + b1_) = o1;
    }
    __syncthreads();
    // ---- MFMA phase ----
    int w = tid >> 6, lane = tid & 63, m = lane & 15, g4 = lane >> 4;
    int cb = w * 32;
    s16x8 BG[2][8];
    #pragma unroll
    for (int nt = 0; nt < 2; nt++)
        #pragma unroll
        for (int j = 0; j < 8; j++)
            BG[nt][j] = *reinterpret_cast<const s16x8*>(&WB2[(size_t)(cb + nt * 16 + m) * D1 + j * 32 + g4 * 8]);
    float bg[2], a1c[2], s1c[2];
    #pragma unroll
    for (int nt = 0; nt < 2; nt++) {
        int col = cb + nt * 16 + m;
        bg[nt] = b2[col]; a1c[nt] = sc1[col]; s1c[nt] = sh1[col];
    }
    float ps[2] = {0.f, 0.f}, pq[2] = {0.f, 0.f};
    #pragma unroll
    for (int rt = 0; rt < 2; rt++) {
        int row = rt * 16 + m;
        s16x8 aA[8];
        #pragma unroll
        for (int j = 0; j < 8; j++) {
            int boff = row * 512 + (((j * 4 + g4) * 16) ^ ((row & 15) << 4));
            aA[j] = *reinterpret_cast<const s16x8*>(((const char*)sA) + boff);
        }
        f32x4 acc[2];
        #pragma unroll
        for (int nt = 0; nt < 2; nt++) acc[nt] = (f32x4){0.f, 0.f, 0.f, 0.f};
        #pragma unroll
        for (int j = 0; j < 8; j++)
            #pragma unroll
            for (int nt = 0; nt < 2; nt++)
                acc[nt] = __builtin_amdgcn_mfma_f32_16x16x32_bf16(aA[j], BG[nt][j], acc[nt], 0, 0, 0);
        #pragma unroll
        for (int nt = 0; nt < 2; nt++) {
            int col = cb + nt * 16 + m;
            #pragma unroll
            for (int r = 0; r < 4; r++) {
                int orow = rbase + rt * 16 + g4 * 4 + r;
                float h1v = fmaf(b2f(t1B[(size_t)orow * D1 + col]), a1c[nt], s1c[nt]);
                float v = gelu_exact(acc[nt][r] + bg[nt]) + h1v;
                t2B[(size_t)orow * D1 + col] = f2b(v);
                ps[nt] += v; pq[nt] += v * v;
            }
        }
    }
    #pragma unroll
    for (int nt = 0; nt < 2; nt++) {
        float s = ps[nt], q = pq[nt];
        s += __shfl_xor(s, 16); s += __shfl_xor(s, 32);
        q += __shfl_xor(q, 16); q += __shfl_xor(q, 32);
        if (g4 == 0) {
            int col = cb + nt * 16 + m;
            partials[(size_t)col * RBLK + blockIdx.x] = s;
            partials[(size_t)(256 + col) * RBLK + blockIdx.x] = q;
        }
    }
}

// ---------- BN reduce: one block per channel ----------

__global__ __launch_bounds__(256) void k_reduce(
    const float* __restrict__ partials, const float* __restrict__ g,
    const float* __restrict__ b, float* __restrict__ sc, float* __restrict__ sh) {
    int c = blockIdx.x;
    int t = threadIdx.x;
    const float* ps = partials + (size_t)c * RBLK;
    const float* pq = partials + (size_t)(256 + c) * RBLK;
    float s = ps[t] + ps[t + 256] + ps[t + 512] + ps[t + 768];
    float q = pq[t] + pq[t + 256] + pq[t + 512] + pq[t + 768];
    __shared__ float Ls[256], Lq[256];
    Ls[t] = s; Lq[t] = q;
    __syncthreads();
    for (int o = 128; o > 0; o >>= 1) {
        if (t < o) { Ls[t] += Ls[t + o]; Lq[t] += Lq[t + o]; }
        __syncthreads();
    }
    if (t == 0) {
        float m = Ls[0] * (1.0f / (float)N_NODES);
        float var = Lq[0] * (1.0f / (float)N_NODES) - m * m;
        float a = g[c] / sqrtf(var + BN_EPS);
        sc[c] = a;
        sh[c] = b[c] - m * a;
    }
}

// ---------- final BN apply: out = sc2*t2 + sh2  (fp32 out) ----------

__global__ __launch_bounds__(256) void k_apply(
    const ushort* __restrict__ t2B, const float* __restrict__ sc,
    const float* __restrict__ sh, float* __restrict__ out) {
    int idx = blockIdx.x * 256 + threadIdx.x;
    size_t base = (size_t)idx * 8;
    int c = (int)(base & 255);
    s16x8 v = *reinterpret_cast<const s16x8*>(&t2B[base]);
    float4 o0, o1;
    o0.x = fmaf(b2f((ushort)v[0]), sc[c + 0], sh[c + 0]);
    o0.y = fmaf(b2f((ushort)v[1]), sc[c + 1], sh[c + 1]);
    o0.z = fmaf(b2f((ushort)v[2]), sc[c + 2], sh[c + 2]);
    o0.w = fmaf(b2f((ushort)v[3]), sc[c + 3], sh[c + 3]);
    o1.x = fmaf(b2f((ushort)v[4]), sc[c + 4], sh[c + 4]);
    o1.y = fmaf(b2f((ushort)v[5]), sc[c + 5], sh[c + 5]);
    o1.z = fmaf(b2f((ushort)v[6]), sc[c + 6], sh[c + 6]);
    o1.w = fmaf(b2f((ushort)v[7]), sc[c + 7], sh[c + 7]);
    *reinterpret_cast<float4*>(&out[base]) = o0;
    *reinterpret_cast<float4*>(&out[base + 4]) = o1;
}

// ---------- launch ----------

static inline size_t align256(size_t x) { return (x + 255) & ~(size_t)255; }

extern "C" void kernel_launch(void* const* d_in, const int* in_sizes, int n_in,
                              void* d_out, int out_size, void* d_ws, size_t ws_size,
                              hipStream_t stream) {
    const float* node_feats = (const float*)d_in[0];
    const float* W_init     = (const float*)d_in[1];
    const float* gcn_w1     = (const float*)d_in[2];
    const float* gcn_b1     = (const float*)d_in[3];
    const float* res_w1     = (const float*)d_in[4];
    const float* res_b1     = (const float*)d_in[5];
    const float* bn_g1      = (const float*)d_in[6];
    const float* bn_b1      = (const float*)d_in[7];
    const float* gcn_w2     = (const float*)d_in[8];
    const float* gcn_b2     = (const float*)d_in[9];
    const float* bn_g2      = (const float*)d_in[10];
    const float* bn_b2      = (const float*)d_in[11];
    const int*   edge_src   = (const int*)d_in[12];
    const int*   edge_dst   = (const int*)d_in[13];
    float* out = (float*)d_out;

    char* p = (char*)d_ws;
    size_t off = 0;
    auto take = [&](size_t bytes) { void* r = p + off; off += align256(bytes); return r; };

    ushort* h0B   = (ushort*)take((size_t)N_NODES * D0 * 2);
    ushort* t1B   = (ushort*)take((size_t)N_NODES * D1 * 2);
    ushort* t2B   = (ushort*)take((size_t)N_NODES * D1 * 2);
    float*  WT    = (float*)take((size_t)F_INF * D0 * 4);
    ushort* WB1   = (ushort*)take((size_t)D1 * D0 * 2);
    ushort* RWB   = (ushort*)take((size_t)D1 * D0 * 2);
    ushort* WB2   = (ushort*)take((size_t)D1 * D1 * 2);
    float*  part1 = (float*)take((size_t)2 * 256 * RBLK * 4);
    float*  part2 = (float*)take((size_t)2 * 256 * RBLK * 4);
    float*  sc1   = (float*)take(256 * 4);
    float*  sh1   = (float*)take(256 * 4);
    float*  sc2   = (float*)take(256 * 4);
    float*  sh2   = (float*)take(256 * 4);
    float*  rsq_out = (float*)take((size_t)N_NODES * 4);
    float*  rsq_in  = (float*)take((size_t)N_NODES * 4);
    int*    degi    = (int*)take((size_t)2 * N_NODES * 4);
    int*    cursor  = (int*)take((size_t)N_NODES * 4);
    int*    row_off = (int*)take((size_t)(N_NODES + 2) * 4);
    int*    csr_src = (int*)take((size_t)E_EDGES * 4);

    hipMemsetAsync(degi, 0, (size_t)2 * N_NODES * 4, stream);

    k_degrees<<<(E_EDGES + 255) / 256, 256, 0, stream>>>(edge_src, edge_dst, degi);
    k_scan<<<1, 1024, 0, stream>>>(degi, row_off, rsq_out, rsq_in, cursor);
    k_fill<<<(E_EDGES + 255) / 256, 256, 0, stream>>>(edge_src, edge_dst, row_off, cursor, csr_src);

    k_prep<<<(D1 * D1) / 256, 256, 0, stream>>>(W_init, gcn_w1, res_w1, gcn_w2, WT, WB1, RWB, WB2);

    k_init_gemm<<<N_NODES / 64, 256, 0, stream>>>(node_feats, WT, h0B);

    k_layer1f<<<RBLK, 512, 0, stream>>>(h0B, rsq_out, rsq_in, row_off, csr_src,
                                        WB1, RWB, gcn_b1, res_b1, t1B, part1);
    k_reduce<<<256, 256, 0, stream>>>(part1, bn_g1, bn_b1, sc1, sh1);

    k_layer2f<<<RBLK, 512, 0, stream>>>(t1B, sc1, sh1, rsq_out, rsq_in, row_off, csr_src,
                                        WB2, gcn_b2, t2B, part2);
    k_reduce<<<256, 256, 0, stream>>>(part2, bn_g2, bn_b2, sc2, sh2);

    k_apply<<<(N_NODES * D1 / 8) / 256, 256, 0, stream>>>(t2B, sc2, sh2, out);
}